// Round 4
// baseline (643.481 us; speedup 1.0000x reference)
//
#include <hip/hip_runtime.h>
#include <hip/hip_bf16.h>
#include <math.h>

#define NB 2
#define NN 512
#define CS 256
#define CP 128
#define FD 64
#define NBINS 22
#define EPB 64

typedef __attribute__((ext_vector_type(8))) short bf16x8;
typedef __attribute__((ext_vector_type(4))) short bf16x4;
typedef __attribute__((ext_vector_type(4))) float f32x4;

__device__ __forceinline__ unsigned short f2bf_rne(float x) {
    unsigned int u = __float_as_uint(x);
    unsigned int r = (u + 0x7fffu + ((u >> 16) & 1u)) >> 16;
    return (unsigned short)r;
}
__device__ __forceinline__ float bf2f(unsigned short b) {
    return __uint_as_float(((unsigned int)b) << 16);
}
// native convert (compiler emits v_cvt_pk_bf16_f32 for pairs)
__device__ __forceinline__ unsigned short f2bf(float x) {
    __hip_bfloat16 h = __float2bfloat16(x);
    unsigned short u;
    __builtin_memcpy(&u, &h, 2);
    return u;
}

// Guarded-floor bin: exact fp32 boundary semantics of the reference scan.
__device__ __forceinline__ int bin_of(float d, float step) {
    const float fk = __fdiv_rn(__fsub_rn(d, 0.001f), step);
    int k0 = (int)fk;
    k0 = k0 < 1 ? 1 : (k0 > 20 ? 20 : k0);
    int row = -1;
    #pragma unroll
    for (int dk = -1; dk <= 1; ++dk) {
        const int k = k0 + dk;
        const float lo = __fadd_rn(0.001f, __fmul_rn((float)k, step));
        const float hi = (k == NBINS - 1)
                       ? 1e8f
                       : __fadd_rn(0.001f, __fmul_rn((float)(k + 1), step));
        row = (d > lo && d < hi) ? k : row;
    }
    return row;
}

// 512B-row LDS swizzle: XOR 16B-granule with row-bits and with boff bits 7-8
// (spreads both cross-row and within-row-chunk accesses across banks).
__device__ __forceinline__ unsigned int swz512(int e, int boff) {
    return (unsigned int)e * 512 +
           (unsigned int)(boff ^ ((e & 7) << 4) ^ (((boff >> 7) & 3) << 4));
}

// ---------------------------------------------------------------------------
// Prep kernel: blocks [0,1024) = per-node q/r precompute; [1024,1088) = W pack.
// ---------------------------------------------------------------------------
__global__ __launch_bounds__(256) void ef_prep_kernel(
    const float* __restrict__ x,
    const float* __restrict__ diffuse,
    const float* __restrict__ Wsp,
    const float* __restrict__ bsp,
    const float* __restrict__ W1,
    const float* __restrict__ b1,
    const float* __restrict__ W2,
    const float* __restrict__ W3,
    float* __restrict__ qr,
    unsigned short* __restrict__ Wp)
{
    __shared__ float xs[CS];
    __shared__ float ps[FD];
    const int t = threadIdx.x;
    if (blockIdx.x < 1024) {
        const int n = blockIdx.x;
        xs[t] = x[(size_t)n * CS + t];
        __syncthreads();
        if (t < FD) {
            float acc = bsp[t];
            #pragma unroll 8
            for (int k = 0; k < CS; ++k)
                acc = fmaf(xs[k], Wsp[k * FD + t], acc);
            ps[t] = acc;
        }
        __syncthreads();
        const float dm = diffuse[n];
        const int c = t & (CP - 1);
        if (t < CP) {
            float acc = b1[c] + dm * W1[172 * CP + c];
            #pragma unroll 8
            for (int k = 0; k < FD; ++k)
                acc = fmaf(ps[k], W1[k * CP + c], acc);
            qr[(size_t)n * CP + c] = acc;
        } else {
            float acc = dm * W1[173 * CP + c];
            #pragma unroll 8
            for (int k = 0; k < FD; ++k)
                acc = fmaf(ps[k], W1[(FD + k) * CP + c], acc);
            qr[(size_t)(1024 + n) * CP + c] = acc;
        }
    } else {
        const int s = (blockIdx.x - 1024) * 256 + t;   // 0..16383
        const int j    = s & 7;
        const int lane = (s >> 3) & 63;
        const int mt   = (s >> 9) & 7;
        const int ki   = s >> 12;
        const int k = 32 * ki + 8 * (lane >> 4) + j;
        const int n = 16 * mt + (lane & 15);
        const float w2 = W2[k * CP + n];
        const float w3 = W3[k * CP + n];
        const unsigned short h2 = f2bf_rne(w2);
        const unsigned short l2 = f2bf_rne(w2 - bf2f(h2));
        const unsigned short h3 = f2bf_rne(w3);
        const unsigned short l3 = f2bf_rne(w3 - bf2f(h3));
        Wp[s]         = h2;
        Wp[16384 + s] = l2;
        Wp[32768 + s] = h3;
        Wp[49152 + s] = l3;
    }
}

// ---------------------------------------------------------------------------
// Edge kernel: persistent (b,i) blocks, loop over 8 j-tiles of 64 edges.
// 256 threads = 4 waves; W2-hi frags register-resident across the loop.
// ---------------------------------------------------------------------------
__global__ __launch_bounds__(256, 4) void ef_edge_kernel(
    const float* __restrict__ trans_t,
    const float* __restrict__ trans_sc,
    const float* __restrict__ edge_mask,
    const float* __restrict__ W1,
    const float* __restrict__ b2,
    const float* __restrict__ b3,
    const float* __restrict__ ln_g,
    const float* __restrict__ ln_b,
    const float* __restrict__ qr,
    const unsigned short* __restrict__ Wp,
    float* __restrict__ out)
{
    __shared__ unsigned short hb[16384];   // exactly 32768 B
    char* hb8 = (char*)hb;

    const int t   = threadIdx.x;
    const int blk = blockIdx.x;
    const int i   = blk & (NN - 1);
    const int b   = blk >> 9;
    const int nodeI = b * NN + i;

    const int w  = t >> 6;
    const int l  = t & 63;
    const int lr = l & 15;
    const int lg = l >> 4;
    const int e1 = t >> 2;
    const int c0 = (t & 3) * 32;

    // ---- persistent W2-hi fragments (loaded once, live across the loop) ----
    bf16x8 w2h[4][2];
    #pragma unroll
    for (int ki = 0; ki < 4; ++ki)
        #pragma unroll
        for (int mt = 0; mt < 2; ++mt)
            w2h[ki][mt] = *(const bf16x8*)(Wp + (((size_t)ki * 8 + (2 * w + mt)) * 64 + l) * 8);

    const float step = __fdiv_rn(__fsub_rn(20.0f, 0.001f), 21.0f);
    const float ix0 = trans_t[nodeI * 3 + 0], ix1 = trans_t[nodeI * 3 + 1], ix2 = trans_t[nodeI * 3 + 2];
    const float iy0 = trans_sc[nodeI * 3 + 0], iy1 = trans_sc[nodeI * 3 + 1], iy2 = trans_sc[nodeI * 3 + 2];
    const float* qrow = qr + (size_t)nodeI * CP + c0;

    #pragma unroll 1
    for (int jt = 0; jt < 8; ++jt) {
        const int j0 = jt * EPB;
        const int nj = b * NN + j0 + e1;

        // ---- bins (per-thread, 4x redundant, no LDS) ----
        float dx = __fsub_rn(ix0, trans_t[nj * 3 + 0]);
        float dy = __fsub_rn(ix1, trans_t[nj * 3 + 1]);
        float dz = __fsub_rn(ix2, trans_t[nj * 3 + 2]);
        const float dT = sqrtf(__fadd_rn(__fadd_rn(__fmul_rn(dx, dx), __fmul_rn(dy, dy)), __fmul_rn(dz, dz)));
        dx = __fsub_rn(iy0, trans_sc[nj * 3 + 0]);
        dy = __fsub_rn(iy1, trans_sc[nj * 3 + 1]);
        dz = __fsub_rn(iy2, trans_sc[nj * 3 + 2]);
        const float dS = sqrtf(__fadd_rn(__fadd_rn(__fmul_rn(dx, dx), __fmul_rn(dy, dy)), __fmul_rn(dz, dz)));
        const int kT = bin_of(dT, step);
        const int kS = bin_of(dS, step);

        // ---- P1: h1 = relu(q_i + r_j + W1[binT] + W1[binS]) -> LDS hi/lo ----
        {
            const float fT = (kT < 0) ? 0.0f : 1.0f;
            const float fS = (kS < 0) ? 0.0f : 1.0f;
            const float* rrow = qr + (size_t)(1024 + nj) * CP + c0;
            const float* wTr  = W1 + (size_t)(kT < 0 ? 0 : 128 + kT) * CP + c0;
            const float* wSr  = W1 + (size_t)(kS < 0 ? 0 : 150 + kS) * CP + c0;
            #pragma unroll
            for (int ch = 0; ch < 4; ++ch) {
                const int cc = ch * 8;
                const float4 qa = *(const float4*)(qrow + cc);
                const float4 qb = *(const float4*)(qrow + cc + 4);
                const float4 ra = *(const float4*)(rrow + cc);
                const float4 rb = *(const float4*)(rrow + cc + 4);
                const float4 ta = *(const float4*)(wTr + cc);
                const float4 tb = *(const float4*)(wTr + cc + 4);
                const float4 sa = *(const float4*)(wSr + cc);
                const float4 sb = *(const float4*)(wSr + cc + 4);
                float h[8];
                h[0] = fmaxf(qa.x + ra.x + fT * ta.x + fS * sa.x, 0.0f);
                h[1] = fmaxf(qa.y + ra.y + fT * ta.y + fS * sa.y, 0.0f);
                h[2] = fmaxf(qa.z + ra.z + fT * ta.z + fS * sa.z, 0.0f);
                h[3] = fmaxf(qa.w + ra.w + fT * ta.w + fS * sa.w, 0.0f);
                h[4] = fmaxf(qb.x + rb.x + fT * tb.x + fS * sb.x, 0.0f);
                h[5] = fmaxf(qb.y + rb.y + fT * tb.y + fS * sb.y, 0.0f);
                h[6] = fmaxf(qb.z + rb.z + fT * tb.z + fS * sb.z, 0.0f);
                h[7] = fmaxf(qb.w + rb.w + fT * tb.w + fS * sb.w, 0.0f);
                bf16x8 H, L;
                #pragma unroll
                for (int u = 0; u < 8; ++u) {
                    const unsigned short hi = f2bf(h[u]);
                    H[u] = (short)hi;
                    L[u] = (short)f2bf(h[u] - bf2f(hi));
                }
                const unsigned int ad = (unsigned int)e1 * 256 +
                    (((unsigned int)(2 * (c0 + cc))) ^ (((unsigned int)e1 & 7) << 4));
                *(bf16x8*)(hb8 + ad) = H;
                *(bf16x8*)(hb8 + 16384 + ad) = L;
            }
        }

        // ---- stream W2-lo fragments (hide under barrier + first MFMAs) ----
        bf16x8 w2l[4][2];
        #pragma unroll
        for (int ki = 0; ki < 4; ++ki)
            #pragma unroll
            for (int mt = 0; mt < 2; ++mt)
                w2l[ki][mt] = *(const bf16x8*)(Wp + 16384 + (((size_t)ki * 8 + (2 * w + mt)) * 64 + l) * 8);
        __syncthreads();

        // ---- P2: layer-2 MFMA, acc init with b2 ----
        f32x4 acc[2][4];
        #pragma unroll
        for (int mt = 0; mt < 2; ++mt) {
            const float4 bv = *(const float4*)&b2[16 * (2 * w + mt) + 4 * lg];
            #pragma unroll
            for (int nt = 0; nt < 4; ++nt) {
                acc[mt][nt][0] = bv.x; acc[mt][nt][1] = bv.y;
                acc[mt][nt][2] = bv.z; acc[mt][nt][3] = bv.w;
            }
        }
        #pragma unroll
        for (int ki = 0; ki < 4; ++ki) {
            bf16x8 bh[4], bl[4];
            #pragma unroll
            for (int nt = 0; nt < 4; ++nt) {
                const int e = 16 * nt + lr;
                const unsigned int ad = (unsigned int)e * 256 +
                    (((unsigned int)(64 * ki + 16 * lg)) ^ (((unsigned int)e & 7) << 4));
                bh[nt] = *(const bf16x8*)(hb8 + ad);
                bl[nt] = *(const bf16x8*)(hb8 + 16384 + ad);
            }
            __builtin_amdgcn_s_setprio(1);
            #pragma unroll
            for (int mt = 0; mt < 2; ++mt)
                #pragma unroll
                for (int nt = 0; nt < 4; ++nt) {
                    acc[mt][nt] = __builtin_amdgcn_mfma_f32_16x16x32_bf16(w2h[ki][mt], bh[nt], acc[mt][nt], 0, 0, 0);
                    acc[mt][nt] = __builtin_amdgcn_mfma_f32_16x16x32_bf16(w2l[ki][mt], bh[nt], acc[mt][nt], 0, 0, 0);
                    acc[mt][nt] = __builtin_amdgcn_mfma_f32_16x16x32_bf16(w2h[ki][mt], bl[nt], acc[mt][nt], 0, 0, 0);
                }
            __builtin_amdgcn_s_setprio(0);
        }

        // ---- stream W3-hi fragments ----
        bf16x8 w3h[4][2];
        #pragma unroll
        for (int ki = 0; ki < 4; ++ki)
            #pragma unroll
            for (int mt = 0; mt < 2; ++mt)
                w3h[ki][mt] = *(const bf16x8*)(Wp + 32768 + (((size_t)ki * 8 + (2 * w + mt)) * 64 + l) * 8);
        __syncthreads();   // all waves done reading h1

        // ---- P3: h2 = relu(acc), split, store transposed [e][n] ----
        #pragma unroll
        for (int mt = 0; mt < 2; ++mt) {
            const int mtg = 2 * w + mt;
            #pragma unroll
            for (int nt = 0; nt < 4; ++nt) {
                const int e = 16 * nt + lr;
                float v[4];
                v[0] = fmaxf(acc[mt][nt][0], 0.0f);
                v[1] = fmaxf(acc[mt][nt][1], 0.0f);
                v[2] = fmaxf(acc[mt][nt][2], 0.0f);
                v[3] = fmaxf(acc[mt][nt][3], 0.0f);
                bf16x4 H, L;
                #pragma unroll
                for (int u = 0; u < 4; ++u) {
                    const unsigned short hi = f2bf(v[u]);
                    H[u] = (short)hi;
                    L[u] = (short)f2bf(v[u] - bf2f(hi));
                }
                const unsigned int ad = (unsigned int)e * 256 +
                    (((unsigned int)(32 * mtg + 8 * lg)) ^ (((unsigned int)e & 7) << 4));
                *(bf16x4*)(hb8 + ad) = H;
                *(bf16x4*)(hb8 + 16384 + ad) = L;
            }
        }

        // ---- stream W3-lo fragments ----
        bf16x8 w3l[4][2];
        #pragma unroll
        for (int ki = 0; ki < 4; ++ki)
            #pragma unroll
            for (int mt = 0; mt < 2; ++mt)
                w3l[ki][mt] = *(const bf16x8*)(Wp + 49152 + (((size_t)ki * 8 + (2 * w + mt)) * 64 + l) * 8);
        __syncthreads();

        // ---- P4: layer-3 MFMA, acc3 init with b3 ----
        f32x4 acc3[2][4];
        #pragma unroll
        for (int mt = 0; mt < 2; ++mt) {
            const float4 bv = *(const float4*)&b3[16 * (2 * w + mt) + 4 * lg];
            #pragma unroll
            for (int nt = 0; nt < 4; ++nt) {
                acc3[mt][nt][0] = bv.x; acc3[mt][nt][1] = bv.y;
                acc3[mt][nt][2] = bv.z; acc3[mt][nt][3] = bv.w;
            }
        }
        #pragma unroll
        for (int ki = 0; ki < 4; ++ki) {
            bf16x8 bh[4], bl[4];
            #pragma unroll
            for (int nt = 0; nt < 4; ++nt) {
                const int e = 16 * nt + lr;
                const unsigned int ad = (unsigned int)e * 256 +
                    (((unsigned int)(64 * ki + 16 * lg)) ^ (((unsigned int)e & 7) << 4));
                bh[nt] = *(const bf16x8*)(hb8 + ad);
                bl[nt] = *(const bf16x8*)(hb8 + 16384 + ad);
            }
            __builtin_amdgcn_s_setprio(1);
            #pragma unroll
            for (int mt = 0; mt < 2; ++mt)
                #pragma unroll
                for (int nt = 0; nt < 4; ++nt) {
                    acc3[mt][nt] = __builtin_amdgcn_mfma_f32_16x16x32_bf16(w3h[ki][mt], bh[nt], acc3[mt][nt], 0, 0, 0);
                    acc3[mt][nt] = __builtin_amdgcn_mfma_f32_16x16x32_bf16(w3l[ki][mt], bh[nt], acc3[mt][nt], 0, 0, 0);
                    acc3[mt][nt] = __builtin_amdgcn_mfma_f32_16x16x32_bf16(w3h[ki][mt], bl[nt], acc3[mt][nt], 0, 0, 0);
                }
            __builtin_amdgcn_s_setprio(0);
        }
        __syncthreads();   // all waves done reading h2; hb reusable

        // ---- P5: h3 (= acc3, biases included) -> LDS f32 [64 e][128 n] ----
        #pragma unroll
        for (int mt = 0; mt < 2; ++mt) {
            const int mtg = 2 * w + mt;
            #pragma unroll
            for (int nt = 0; nt < 4; ++nt) {
                const int e = 16 * nt + lr;
                float4 vv;
                vv.x = acc3[mt][nt][0]; vv.y = acc3[mt][nt][1];
                vv.z = acc3[mt][nt][2]; vv.w = acc3[mt][nt][3];
                *(float4*)(hb8 + swz512(e, 64 * mtg + 16 * lg)) = vv;
            }
        }
        __syncthreads();

        // ---- P6: LayerNorm (exact two-pass fp32), mask, coalesced store ----
        {
            const int e = e1;
            float vals[32];
            float s = 0.0f;
            #pragma unroll
            for (int cc = 0; cc < 32; cc += 4) {
                const float4 v = *(const float4*)(hb8 + swz512(e, 4 * (c0 + cc)));
                vals[cc] = v.x; vals[cc + 1] = v.y; vals[cc + 2] = v.z; vals[cc + 3] = v.w;
                s += v.x + v.y + v.z + v.w;
            }
            s += __shfl_xor(s, 1);
            s += __shfl_xor(s, 2);
            const float mu = s * (1.0f / 128.0f);
            float s2 = 0.0f;
            #pragma unroll
            for (int cc = 0; cc < 32; ++cc) {
                const float d = vals[cc] - mu;
                s2 = fmaf(d, d, s2);
            }
            s2 += __shfl_xor(s2, 1);
            s2 += __shfl_xor(s2, 2);
            const float inv = rsqrtf(s2 * (1.0f / 128.0f) + 1e-5f);
            const size_t erow = ((size_t)(b * NN + i)) * NN + (j0 + e);
            const float em = edge_mask[erow];
            float* op = out + erow * CP + c0;
            #pragma unroll
            for (int cc = 0; cc < 32; cc += 4) {
                const float4 g  = *(const float4*)&ln_g[c0 + cc];
                const float4 be = *(const float4*)&ln_b[c0 + cc];
                float4 o4;
                o4.x = ((vals[cc + 0] - mu) * inv * g.x + be.x) * em;
                o4.y = ((vals[cc + 1] - mu) * inv * g.y + be.y) * em;
                o4.z = ((vals[cc + 2] - mu) * inv * g.z + be.z) * em;
                o4.w = ((vals[cc + 3] - mu) * inv * g.w + be.w) * em;
                *(float4*)&op[cc] = o4;
            }
        }
        __syncthreads();   // protect hb before next iteration's h1 writes
    }
}

extern "C" void kernel_launch(void* const* d_in, const int* in_sizes, int n_in,
                              void* d_out, int out_size, void* d_ws, size_t ws_size,
                              hipStream_t stream) {
    const float* init_node = (const float*)d_in[0];
    const float* trans_t   = (const float*)d_in[1];
    const float* trans_sc  = (const float*)d_in[2];
    const float* edge_mask = (const float*)d_in[3];
    const float* diffuse   = (const float*)d_in[4];
    const float* Wsp       = (const float*)d_in[5];
    const float* bsp       = (const float*)d_in[6];
    const float* W1        = (const float*)d_in[7];
    const float* b1        = (const float*)d_in[8];
    const float* W2        = (const float*)d_in[9];
    const float* b2        = (const float*)d_in[10];
    const float* W3        = (const float*)d_in[11];
    const float* b3        = (const float*)d_in[12];
    const float* ln_g      = (const float*)d_in[13];
    const float* ln_b      = (const float*)d_in[14];
    float* out = (float*)d_out;
    float* qr  = (float*)d_ws;                                       // 1 MiB
    unsigned short* Wp = (unsigned short*)((char*)d_ws + (1 << 20)); // 128 KiB

    ef_prep_kernel<<<1024 + 64, 256, 0, stream>>>(
        init_node, diffuse, Wsp, bsp, W1, b1, W2, W3, qr, Wp);
    ef_edge_kernel<<<NB * NN, 256, 0, stream>>>(
        trans_t, trans_sc, edge_mask, W1, b2, b3, ln_g, ln_b, qr, Wp, out);
}

// Round 5
// 294.190 us; speedup vs baseline: 2.1873x; 2.1873x over previous
//
#include <hip/hip_runtime.h>
#include <hip/hip_bf16.h>
#include <math.h>

#define NB 2
#define NN 512
#define CS 256
#define CP 128
#define FD 64
#define NBINS 22
#define EPB 64

typedef __attribute__((ext_vector_type(8))) short bf16x8;
typedef __attribute__((ext_vector_type(4))) short bf16x4;
typedef __attribute__((ext_vector_type(4))) float f32x4;

__device__ __forceinline__ unsigned short f2bf_rne(float x) {
    unsigned int u = __float_as_uint(x);
    unsigned int r = (u + 0x7fffu + ((u >> 16) & 1u)) >> 16;
    return (unsigned short)r;
}
__device__ __forceinline__ float bf2f(unsigned short b) {
    return __uint_as_float(((unsigned int)b) << 16);
}
// native convert (compiler can pack pairs into v_cvt_pk_bf16_f32)
__device__ __forceinline__ unsigned short f2bf(float x) {
    __hip_bfloat16 h = __float2bfloat16(x);
    unsigned short u;
    __builtin_memcpy(&u, &h, 2);
    return u;
}

// Guarded-floor bin: exact fp32 boundary semantics of the reference scan.
__device__ __forceinline__ int bin_of(float d, float step) {
    const float fk = __fdiv_rn(__fsub_rn(d, 0.001f), step);
    int k0 = (int)fk;
    k0 = k0 < 1 ? 1 : (k0 > 20 ? 20 : k0);
    int row = -1;
    #pragma unroll
    for (int dk = -1; dk <= 1; ++dk) {
        const int k = k0 + dk;
        const float lo = __fadd_rn(0.001f, __fmul_rn((float)k, step));
        const float hi = (k == NBINS - 1)
                       ? 1e8f
                       : __fadd_rn(0.001f, __fmul_rn((float)(k + 1), step));
        row = (d > lo && d < hi) ? k : row;
    }
    return row;
}

// 512B-row LDS swizzle for the f32 h3 staging tile.
__device__ __forceinline__ unsigned int swz512(int e, int boff) {
    return (unsigned int)e * 512 +
           (unsigned int)(boff ^ ((e & 7) << 4) ^ (((boff >> 7) & 3) << 4));
}

// ---------------------------------------------------------------------------
// Prep kernel: blocks [0,1024) = per-node q/r precompute; [1024,1088) = W pack.
//   q[n,c] = b1[c] + diffuse[n]*W1[172,c] + sum_k p[n,k]*W1[k,c]
//   r[n,c] =         diffuse[n]*W1[173,c] + sum_k p[n,k]*W1[64+k,c]
// Wp: [4][16384] ushort {W2h, W2l, W3h, W3l}, per-lane MFMA A-frag order.
// ---------------------------------------------------------------------------
__global__ __launch_bounds__(256) void ef_prep_kernel(
    const float* __restrict__ x,
    const float* __restrict__ diffuse,
    const float* __restrict__ Wsp,
    const float* __restrict__ bsp,
    const float* __restrict__ W1,
    const float* __restrict__ b1,
    const float* __restrict__ W2,
    const float* __restrict__ W3,
    float* __restrict__ qr,
    unsigned short* __restrict__ Wp)
{
    __shared__ float xs[CS];
    __shared__ float ps[FD];
    const int t = threadIdx.x;
    if (blockIdx.x < 1024) {
        const int n = blockIdx.x;
        xs[t] = x[(size_t)n * CS + t];
        __syncthreads();
        if (t < FD) {
            float acc = bsp[t];
            #pragma unroll 8
            for (int k = 0; k < CS; ++k)
                acc = fmaf(xs[k], Wsp[k * FD + t], acc);
            ps[t] = acc;
        }
        __syncthreads();
        const float dm = diffuse[n];
        const int c = t & (CP - 1);
        if (t < CP) {
            float acc = b1[c] + dm * W1[172 * CP + c];
            #pragma unroll 8
            for (int k = 0; k < FD; ++k)
                acc = fmaf(ps[k], W1[k * CP + c], acc);
            qr[(size_t)n * CP + c] = acc;
        } else {
            float acc = dm * W1[173 * CP + c];
            #pragma unroll 8
            for (int k = 0; k < FD; ++k)
                acc = fmaf(ps[k], W1[(FD + k) * CP + c], acc);
            qr[(size_t)(1024 + n) * CP + c] = acc;
        }
    } else {
        const int s = (blockIdx.x - 1024) * 256 + t;   // 0..16383
        const int j    = s & 7;
        const int lane = (s >> 3) & 63;
        const int mt   = (s >> 9) & 7;
        const int ki   = s >> 12;
        const int k = 32 * ki + 8 * (lane >> 4) + j;
        const int n = 16 * mt + (lane & 15);
        const float w2 = W2[k * CP + n];
        const float w3 = W3[k * CP + n];
        const unsigned short h2 = f2bf_rne(w2);
        const unsigned short l2 = f2bf_rne(w2 - bf2f(h2));
        const unsigned short h3 = f2bf_rne(w3);
        const unsigned short l3 = f2bf_rne(w3 - bf2f(h3));
        Wp[s]         = h2;
        Wp[16384 + s] = l2;
        Wp[32768 + s] = h3;
        Wp[49152 + s] = l3;
    }
}

// ---------------------------------------------------------------------------
// Edge kernel: one 64-edge tile per block (fixed b,i; 64 j's), 4 waves.
// Shared accumulator across both GEMMs keeps unified VGPR+AGPR <= ~96
// so 5 waves/SIMD can be resident (launch_bounds(256,5)).
// ---------------------------------------------------------------------------
__global__ __launch_bounds__(256, 5) void ef_edge_kernel(
    const float* __restrict__ trans_t,
    const float* __restrict__ trans_sc,
    const float* __restrict__ edge_mask,
    const float* __restrict__ W1,
    const float* __restrict__ b2,
    const float* __restrict__ b3,
    const float* __restrict__ ln_g,
    const float* __restrict__ ln_b,
    const float* __restrict__ qr,
    const unsigned short* __restrict__ Wp,
    float* __restrict__ out)
{
    __shared__ unsigned short hb[16384];   // exactly 32768 B
    char* hb8 = (char*)hb;

    const int t   = threadIdx.x;
    const int blk = blockIdx.x;
    const int jt  = blk & 7;
    const int i   = (blk >> 3) & (NN - 1);
    const int b   = blk >> 12;
    const int j0  = jt * EPB;
    const int nodeI  = b * NN + i;
    const int nodeJ0 = b * NN + j0;

    const int w  = t >> 6;
    const int l  = t & 63;
    const int lr = l & 15;
    const int lg = l >> 4;
    const int e1 = t >> 2;
    const int c0 = (t & 3) * 32;
    const int nj = nodeJ0 + e1;

    // ---- bins (per-thread, 4x redundant, no LDS, no barrier) ----
    const float step = __fdiv_rn(__fsub_rn(20.0f, 0.001f), 21.0f);
    {
    }
    float dx = __fsub_rn(trans_t[nodeI * 3 + 0], trans_t[nj * 3 + 0]);
    float dy = __fsub_rn(trans_t[nodeI * 3 + 1], trans_t[nj * 3 + 1]);
    float dz = __fsub_rn(trans_t[nodeI * 3 + 2], trans_t[nj * 3 + 2]);
    const float dT = sqrtf(__fadd_rn(__fadd_rn(__fmul_rn(dx, dx), __fmul_rn(dy, dy)), __fmul_rn(dz, dz)));
    dx = __fsub_rn(trans_sc[nodeI * 3 + 0], trans_sc[nj * 3 + 0]);
    dy = __fsub_rn(trans_sc[nodeI * 3 + 1], trans_sc[nj * 3 + 1]);
    dz = __fsub_rn(trans_sc[nodeI * 3 + 2], trans_sc[nj * 3 + 2]);
    const float dS = sqrtf(__fadd_rn(__fadd_rn(__fmul_rn(dx, dx), __fmul_rn(dy, dy)), __fmul_rn(dz, dz)));
    const int kT = bin_of(dT, step);
    const int kS = bin_of(dS, step);

    // ---- P1: h1 = relu(q_i + r_j + W1[binT] + W1[binS]) -> LDS hi/lo ----
    {
        const float fT = (kT < 0) ? 0.0f : 1.0f;
        const float fS = (kS < 0) ? 0.0f : 1.0f;
        const float* qrow = qr + (size_t)nodeI * CP + c0;
        const float* rrow = qr + (size_t)(1024 + nj) * CP + c0;
        const float* wTr  = W1 + (size_t)(kT < 0 ? 0 : 128 + kT) * CP + c0;
        const float* wSr  = W1 + (size_t)(kS < 0 ? 0 : 150 + kS) * CP + c0;
        #pragma unroll
        for (int ch = 0; ch < 4; ++ch) {
            const int cc = ch * 8;
            const float4 qa = *(const float4*)(qrow + cc);
            const float4 qb = *(const float4*)(qrow + cc + 4);
            const float4 ra = *(const float4*)(rrow + cc);
            const float4 rb = *(const float4*)(rrow + cc + 4);
            const float4 ta = *(const float4*)(wTr + cc);
            const float4 tb = *(const float4*)(wTr + cc + 4);
            const float4 sa = *(const float4*)(wSr + cc);
            const float4 sb = *(const float4*)(wSr + cc + 4);
            float h[8];
            h[0] = fmaxf(qa.x + ra.x + fT * ta.x + fS * sa.x, 0.0f);
            h[1] = fmaxf(qa.y + ra.y + fT * ta.y + fS * sa.y, 0.0f);
            h[2] = fmaxf(qa.z + ra.z + fT * ta.z + fS * sa.z, 0.0f);
            h[3] = fmaxf(qa.w + ra.w + fT * ta.w + fS * sa.w, 0.0f);
            h[4] = fmaxf(qb.x + rb.x + fT * tb.x + fS * sb.x, 0.0f);
            h[5] = fmaxf(qb.y + rb.y + fT * tb.y + fS * sb.y, 0.0f);
            h[6] = fmaxf(qb.z + rb.z + fT * tb.z + fS * sb.z, 0.0f);
            h[7] = fmaxf(qb.w + rb.w + fT * tb.w + fS * sb.w, 0.0f);
            bf16x8 H, L;
            #pragma unroll
            for (int u = 0; u < 8; ++u) {
                const unsigned short hi = f2bf(h[u]);
                H[u] = (short)hi;
                L[u] = (short)f2bf(h[u] - bf2f(hi));
            }
            const unsigned int ad = (unsigned int)e1 * 256 +
                (((unsigned int)(2 * (c0 + cc))) ^ (((unsigned int)e1 & 7) << 4));
            *(bf16x8*)(hb8 + ad) = H;
            *(bf16x8*)(hb8 + 16384 + ad) = L;
        }
    }
    __syncthreads();

    // ---- P2: layer-2 MFMA; shared acc (re-used for layer 3 later) ----
    f32x4 acc[2][4];
    #pragma unroll
    for (int mt = 0; mt < 2; ++mt) {
        const float4 bv = *(const float4*)&b2[16 * (2 * w + mt) + 4 * lg];
        #pragma unroll
        for (int nt = 0; nt < 4; ++nt) {
            acc[mt][nt][0] = bv.x; acc[mt][nt][1] = bv.y;
            acc[mt][nt][2] = bv.z; acc[mt][nt][3] = bv.w;
        }
    }
    #pragma unroll
    for (int ki = 0; ki < 4; ++ki) {
        bf16x8 ah[2], al[2];
        #pragma unroll
        for (int mt = 0; mt < 2; ++mt) {
            const size_t off = (((size_t)ki * 8 + (2 * w + mt)) * 64 + l) * 8;
            ah[mt] = *(const bf16x8*)(Wp + off);
            al[mt] = *(const bf16x8*)(Wp + 16384 + off);
        }
        bf16x8 bh[4], bl[4];
        #pragma unroll
        for (int nt = 0; nt < 4; ++nt) {
            const int e = 16 * nt + lr;
            const unsigned int ad = (unsigned int)e * 256 +
                (((unsigned int)(64 * ki + 16 * lg)) ^ (((unsigned int)e & 7) << 4));
            bh[nt] = *(const bf16x8*)(hb8 + ad);
            bl[nt] = *(const bf16x8*)(hb8 + 16384 + ad);
        }
        __builtin_amdgcn_s_setprio(1);
        #pragma unroll
        for (int mt = 0; mt < 2; ++mt)
            #pragma unroll
            for (int nt = 0; nt < 4; ++nt) {
                acc[mt][nt] = __builtin_amdgcn_mfma_f32_16x16x32_bf16(ah[mt], bh[nt], acc[mt][nt], 0, 0, 0);
                acc[mt][nt] = __builtin_amdgcn_mfma_f32_16x16x32_bf16(al[mt], bh[nt], acc[mt][nt], 0, 0, 0);
                acc[mt][nt] = __builtin_amdgcn_mfma_f32_16x16x32_bf16(ah[mt], bl[nt], acc[mt][nt], 0, 0, 0);
            }
        __builtin_amdgcn_s_setprio(0);
    }
    __syncthreads();   // all waves done reading h1; hb reusable for h2

    // ---- P3: h2 = relu(acc), split, store transposed [e][n] hi/lo ----
    #pragma unroll
    for (int mt = 0; mt < 2; ++mt) {
        const int mtg = 2 * w + mt;
        #pragma unroll
        for (int nt = 0; nt < 4; ++nt) {
            const int e = 16 * nt + lr;
            float v[4];
            v[0] = fmaxf(acc[mt][nt][0], 0.0f);
            v[1] = fmaxf(acc[mt][nt][1], 0.0f);
            v[2] = fmaxf(acc[mt][nt][2], 0.0f);
            v[3] = fmaxf(acc[mt][nt][3], 0.0f);
            bf16x4 H, L;
            #pragma unroll
            for (int u = 0; u < 4; ++u) {
                const unsigned short hi = f2bf(v[u]);
                H[u] = (short)hi;
                L[u] = (short)f2bf(v[u] - bf2f(hi));
            }
            const unsigned int ad = (unsigned int)e * 256 +
                (((unsigned int)(32 * mtg + 8 * lg)) ^ (((unsigned int)e & 7) << 4));
            *(bf16x4*)(hb8 + ad) = H;
            *(bf16x4*)(hb8 + 16384 + ad) = L;
        }
    }
    __syncthreads();

    // ---- P4: layer-3 MFMA into the SAME acc (re-init with b3) ----
    #pragma unroll
    for (int mt = 0; mt < 2; ++mt) {
        const float4 bv = *(const float4*)&b3[16 * (2 * w + mt) + 4 * lg];
        #pragma unroll
        for (int nt = 0; nt < 4; ++nt) {
            acc[mt][nt][0] = bv.x; acc[mt][nt][1] = bv.y;
            acc[mt][nt][2] = bv.z; acc[mt][nt][3] = bv.w;
        }
    }
    #pragma unroll
    for (int ki = 0; ki < 4; ++ki) {
        bf16x8 ah[2], al[2];
        #pragma unroll
        for (int mt = 0; mt < 2; ++mt) {
            const size_t off = (((size_t)ki * 8 + (2 * w + mt)) * 64 + l) * 8;
            ah[mt] = *(const bf16x8*)(Wp + 32768 + off);
            al[mt] = *(const bf16x8*)(Wp + 49152 + off);
        }
        bf16x8 bh[4], bl[4];
        #pragma unroll
        for (int nt = 0; nt < 4; ++nt) {
            const int e = 16 * nt + lr;
            const unsigned int ad = (unsigned int)e * 256 +
                (((unsigned int)(64 * ki + 16 * lg)) ^ (((unsigned int)e & 7) << 4));
            bh[nt] = *(const bf16x8*)(hb8 + ad);
            bl[nt] = *(const bf16x8*)(hb8 + 16384 + ad);
        }
        __builtin_amdgcn_s_setprio(1);
        #pragma unroll
        for (int mt = 0; mt < 2; ++mt)
            #pragma unroll
            for (int nt = 0; nt < 4; ++nt) {
                acc[mt][nt] = __builtin_amdgcn_mfma_f32_16x16x32_bf16(ah[mt], bh[nt], acc[mt][nt], 0, 0, 0);
                acc[mt][nt] = __builtin_amdgcn_mfma_f32_16x16x32_bf16(al[mt], bh[nt], acc[mt][nt], 0, 0, 0);
                acc[mt][nt] = __builtin_amdgcn_mfma_f32_16x16x32_bf16(ah[mt], bl[nt], acc[mt][nt], 0, 0, 0);
            }
        __builtin_amdgcn_s_setprio(0);
    }
    __syncthreads();   // all waves done reading h2; hb reusable for h3

    // ---- P5: h3 (biases already in acc) -> LDS f32 [64 e][128 n] ----
    #pragma unroll
    for (int mt = 0; mt < 2; ++mt) {
        const int mtg = 2 * w + mt;
        #pragma unroll
        for (int nt = 0; nt < 4; ++nt) {
            const int e = 16 * nt + lr;
            float4 vv;
            vv.x = acc[mt][nt][0]; vv.y = acc[mt][nt][1];
            vv.z = acc[mt][nt][2]; vv.w = acc[mt][nt][3];
            *(float4*)(hb8 + swz512(e, 64 * mtg + 16 * lg)) = vv;
        }
    }
    __syncthreads();

    // ---- P6: LayerNorm (exact two-pass fp32), mask, coalesced store ----
    {
        const int e = e1;
        float vals[32];
        float s = 0.0f;
        #pragma unroll
        for (int cc = 0; cc < 32; cc += 4) {
            const float4 v = *(const float4*)(hb8 + swz512(e, 4 * (c0 + cc)));
            vals[cc] = v.x; vals[cc + 1] = v.y; vals[cc + 2] = v.z; vals[cc + 3] = v.w;
            s += v.x + v.y + v.z + v.w;
        }
        s += __shfl_xor(s, 1);
        s += __shfl_xor(s, 2);
        const float mu = s * (1.0f / 128.0f);
        float s2 = 0.0f;
        #pragma unroll
        for (int cc = 0; cc < 32; ++cc) {
            const float d = vals[cc] - mu;
            s2 = fmaf(d, d, s2);
        }
        s2 += __shfl_xor(s2, 1);
        s2 += __shfl_xor(s2, 2);
        const float inv = rsqrtf(s2 * (1.0f / 128.0f) + 1e-5f);
        const size_t erow = ((size_t)(b * NN + i)) * NN + (j0 + e);
        const float em = edge_mask[erow];
        float* op = out + erow * CP + c0;
        #pragma unroll
        for (int cc = 0; cc < 32; cc += 4) {
            const float4 g  = *(const float4*)&ln_g[c0 + cc];
            const float4 be = *(const float4*)&ln_b[c0 + cc];
            float4 o4;
            o4.x = ((vals[cc + 0] - mu) * inv * g.x + be.x) * em;
            o4.y = ((vals[cc + 1] - mu) * inv * g.y + be.y) * em;
            o4.z = ((vals[cc + 2] - mu) * inv * g.z + be.z) * em;
            o4.w = ((vals[cc + 3] - mu) * inv * g.w + be.w) * em;
            *(float4*)&op[cc] = o4;
        }
    }
}

extern "C" void kernel_launch(void* const* d_in, const int* in_sizes, int n_in,
                              void* d_out, int out_size, void* d_ws, size_t ws_size,
                              hipStream_t stream) {
    const float* init_node = (const float*)d_in[0];
    const float* trans_t   = (const float*)d_in[1];
    const float* trans_sc  = (const float*)d_in[2];
    const float* edge_mask = (const float*)d_in[3];
    const float* diffuse   = (const float*)d_in[4];
    const float* Wsp       = (const float*)d_in[5];
    const float* bsp       = (const float*)d_in[6];
    const float* W1        = (const float*)d_in[7];
    const float* b1        = (const float*)d_in[8];
    const float* W2        = (const float*)d_in[9];
    const float* b2        = (const float*)d_in[10];
    const float* W3        = (const float*)d_in[11];
    const float* b3        = (const float*)d_in[12];
    const float* ln_g      = (const float*)d_in[13];
    const float* ln_b      = (const float*)d_in[14];
    float* out = (float*)d_out;
    float* qr  = (float*)d_ws;                                       // 1 MiB
    unsigned short* Wp = (unsigned short*)((char*)d_ws + (1 << 20)); // 128 KiB

    ef_prep_kernel<<<1024 + 64, 256, 0, stream>>>(
        init_node, diffuse, Wsp, bsp, W1, b1, W2, W3, qr, Wp);
    ef_edge_kernel<<<NB * NN * (NN / EPB), 256, 0, stream>>>(
        trans_t, trans_sc, edge_mask, W1, b2, b3, ln_g, ln_b, qr, Wp, out);
}

// Round 6
// 282.561 us; speedup vs baseline: 2.2773x; 1.0412x over previous
//
#include <hip/hip_runtime.h>
#include <hip/hip_bf16.h>
#include <math.h>

#define NB 2
#define NN 512
#define CS 256
#define CP 128
#define FD 64
#define NBINS 22
#define EPB 64

typedef __attribute__((ext_vector_type(8))) short bf16x8;
typedef __attribute__((ext_vector_type(4))) short bf16x4;
typedef __attribute__((ext_vector_type(4))) float f32x4;

__device__ __forceinline__ unsigned short f2bf_rne(float x) {
    unsigned int u = __float_as_uint(x);
    unsigned int r = (u + 0x7fffu + ((u >> 16) & 1u)) >> 16;
    return (unsigned short)r;
}
__device__ __forceinline__ float bf2f(unsigned short b) {
    return __uint_as_float(((unsigned int)b) << 16);
}
__device__ __forceinline__ unsigned short f2bf(float x) {
    __hip_bfloat16 h = __float2bfloat16(x);
    unsigned short u;
    __builtin_memcpy(&u, &h, 2);
    return u;
}

// Guarded-floor bin: exact fp32 boundary semantics of the reference scan.
__device__ __forceinline__ int bin_of(float d, float step) {
    const float fk = __fdiv_rn(__fsub_rn(d, 0.001f), step);
    int k0 = (int)fk;
    k0 = k0 < 1 ? 1 : (k0 > 20 ? 20 : k0);
    int row = -1;
    #pragma unroll
    for (int dk = -1; dk <= 1; ++dk) {
        const int k = k0 + dk;
        const float lo = __fadd_rn(0.001f, __fmul_rn((float)k, step));
        const float hi = (k == NBINS - 1)
                       ? 1e8f
                       : __fadd_rn(0.001f, __fmul_rn((float)(k + 1), step));
        row = (d > lo && d < hi) ? k : row;
    }
    return row;
}

// ---------------------------------------------------------------------------
// Prep kernel: blocks [0,1024) = per-node q/r precompute; [1024,1088) = W pack.
// ---------------------------------------------------------------------------
__global__ __launch_bounds__(256) void ef_prep_kernel(
    const float* __restrict__ x,
    const float* __restrict__ diffuse,
    const float* __restrict__ Wsp,
    const float* __restrict__ bsp,
    const float* __restrict__ W1,
    const float* __restrict__ b1,
    const float* __restrict__ W2,
    const float* __restrict__ W3,
    float* __restrict__ qr,
    unsigned short* __restrict__ Wp)
{
    __shared__ float xs[CS];
    __shared__ float ps[FD];
    const int t = threadIdx.x;
    if (blockIdx.x < 1024) {
        const int n = blockIdx.x;
        xs[t] = x[(size_t)n * CS + t];
        __syncthreads();
        if (t < FD) {
            float acc = bsp[t];
            #pragma unroll 8
            for (int k = 0; k < CS; ++k)
                acc = fmaf(xs[k], Wsp[k * FD + t], acc);
            ps[t] = acc;
        }
        __syncthreads();
        const float dm = diffuse[n];
        const int c = t & (CP - 1);
        if (t < CP) {
            float acc = b1[c] + dm * W1[172 * CP + c];
            #pragma unroll 8
            for (int k = 0; k < FD; ++k)
                acc = fmaf(ps[k], W1[k * CP + c], acc);
            qr[(size_t)n * CP + c] = acc;
        } else {
            float acc = dm * W1[173 * CP + c];
            #pragma unroll 8
            for (int k = 0; k < FD; ++k)
                acc = fmaf(ps[k], W1[(FD + k) * CP + c], acc);
            qr[(size_t)(1024 + n) * CP + c] = acc;
        }
    } else {
        const int s = (blockIdx.x - 1024) * 256 + t;   // 0..16383
        const int j    = s & 7;
        const int lane = (s >> 3) & 63;
        const int mt   = (s >> 9) & 7;
        const int ki   = s >> 12;
        const int k = 32 * ki + 8 * (lane >> 4) + j;
        const int n = 16 * mt + (lane & 15);
        const float w2 = W2[k * CP + n];
        const float w3 = W3[k * CP + n];
        const unsigned short h2 = f2bf_rne(w2);
        const unsigned short l2 = f2bf_rne(w2 - bf2f(h2));
        const unsigned short h3 = f2bf_rne(w3);
        const unsigned short l3 = f2bf_rne(w3 - bf2f(h3));
        Wp[s]         = h2;
        Wp[16384 + s] = l2;
        Wp[32768 + s] = h3;
        Wp[49152 + s] = l3;
    }
}

// ---------------------------------------------------------------------------
// Edge kernel, barrier-minimal wave-split.
// Block: 64 edges (fixed b,i). 4 waves; wave w = (mh = w>>1, eh = w&1):
//   owns n in [64*mh, 64*mh+64) x edges [32*eh, 32*eh+32).
// h1 built IN REGISTERS in B-frag layout (lane lr = edge, lg = k-group).
// Only 2 barriers: h2 exchange (shared LDS) and LN cross-wave combine.
// ---------------------------------------------------------------------------
__global__ __launch_bounds__(256, 4) void ef_edge_kernel(
    const float* __restrict__ trans_t,
    const float* __restrict__ trans_sc,
    const float* __restrict__ edge_mask,
    const float* __restrict__ W1,
    const float* __restrict__ b2,
    const float* __restrict__ b3,
    const float* __restrict__ ln_g,
    const float* __restrict__ ln_b,
    const float* __restrict__ qr,
    const unsigned short* __restrict__ Wp,
    float* __restrict__ out)
{
    __shared__ char hb8[33792];   // h2 hi [0,16K), h2 lo [16K,32K), LN [32K,33K)
    float* lnS = (float*)(hb8 + 32768);   // [64][2]
    float* lnQ = (float*)(hb8 + 33280);   // [64][2]

    const int t   = threadIdx.x;
    const int blk = blockIdx.x;
    const int jt  = blk & 7;
    const int i   = (blk >> 3) & (NN - 1);
    const int b   = blk >> 12;
    const int j0  = jt * EPB;
    const int nodeI  = b * NN + i;
    const int nodeJ0 = b * NN + j0;

    const int w  = t >> 6;
    const int l  = t & 63;
    const int lr = l & 15;
    const int lg = l >> 4;
    const int mh = w >> 1;          // n-half
    const int eh = w & 1;           // edge-half

    // ---- bins for this lane's two edges (nt = 0,1) ----
    const float step = __fdiv_rn(__fsub_rn(20.0f, 0.001f), 21.0f);
    const float ix0 = trans_t[nodeI * 3 + 0], ix1 = trans_t[nodeI * 3 + 1], ix2 = trans_t[nodeI * 3 + 2];
    const float iy0 = trans_sc[nodeI * 3 + 0], iy1 = trans_sc[nodeI * 3 + 1], iy2 = trans_sc[nodeI * 3 + 2];
    int njv[2], kT[2], kS[2];
    #pragma unroll
    for (int nt = 0; nt < 2; ++nt) {
        const int eloc = 32 * eh + 16 * nt + lr;
        const int nj = nodeJ0 + eloc;
        njv[nt] = nj;
        float dx = __fsub_rn(ix0, trans_t[nj * 3 + 0]);
        float dy = __fsub_rn(ix1, trans_t[nj * 3 + 1]);
        float dz = __fsub_rn(ix2, trans_t[nj * 3 + 2]);
        const float dT = sqrtf(__fadd_rn(__fadd_rn(__fmul_rn(dx, dx), __fmul_rn(dy, dy)), __fmul_rn(dz, dz)));
        dx = __fsub_rn(iy0, trans_sc[nj * 3 + 0]);
        dy = __fsub_rn(iy1, trans_sc[nj * 3 + 1]);
        dz = __fsub_rn(iy2, trans_sc[nj * 3 + 2]);
        const float dS = sqrtf(__fadd_rn(__fadd_rn(__fmul_rn(dx, dx), __fmul_rn(dy, dy)), __fmul_rn(dz, dz)));
        kT[nt] = bin_of(dT, step);
        kS[nt] = bin_of(dS, step);
    }

    const float* qrow = qr + (size_t)nodeI * CP;

    // ---- layer 2: acc[m][nt], n = 64*mh + 16*m + 4*lg + r ----
    f32x4 acc[4][2];
    #pragma unroll
    for (int m = 0; m < 4; ++m) {
        const float4 bv = *(const float4*)&b2[64 * mh + 16 * m + 4 * lg];
        #pragma unroll
        for (int nt = 0; nt < 2; ++nt) {
            acc[m][nt][0] = bv.x; acc[m][nt][1] = bv.y;
            acc[m][nt][2] = bv.z; acc[m][nt][3] = bv.w;
        }
    }

    #pragma unroll
    for (int kp = 0; kp < 2; ++kp) {
        // build B-frags (h1) in registers for ki = 2kp, 2kp+1
        bf16x8 Bh[2][2], Bl[2][2];   // [nt][kii]
        #pragma unroll
        for (int kii = 0; kii < 2; ++kii) {
            const int ki = 2 * kp + kii;
            const int k0 = 32 * ki + 8 * lg;
            const float4 qa = *(const float4*)(qrow + k0);
            const float4 qb = *(const float4*)(qrow + k0 + 4);
            #pragma unroll
            for (int nt = 0; nt < 2; ++nt) {
                const float fT = (kT[nt] < 0) ? 0.0f : 1.0f;
                const float fS = (kS[nt] < 0) ? 0.0f : 1.0f;
                const float* rrow = qr + (size_t)(1024 + njv[nt]) * CP + k0;
                const float* wTr  = W1 + (size_t)(kT[nt] < 0 ? 0 : 128 + kT[nt]) * CP + k0;
                const float* wSr  = W1 + (size_t)(kS[nt] < 0 ? 0 : 150 + kS[nt]) * CP + k0;
                const float4 ra = *(const float4*)(rrow);
                const float4 rb = *(const float4*)(rrow + 4);
                const float4 ta = *(const float4*)(wTr);
                const float4 tb = *(const float4*)(wTr + 4);
                const float4 sa = *(const float4*)(wSr);
                const float4 sb = *(const float4*)(wSr + 4);
                float h[8];
                h[0] = fmaxf(qa.x + ra.x + fT * ta.x + fS * sa.x, 0.0f);
                h[1] = fmaxf(qa.y + ra.y + fT * ta.y + fS * sa.y, 0.0f);
                h[2] = fmaxf(qa.z + ra.z + fT * ta.z + fS * sa.z, 0.0f);
                h[3] = fmaxf(qa.w + ra.w + fT * ta.w + fS * sa.w, 0.0f);
                h[4] = fmaxf(qb.x + rb.x + fT * tb.x + fS * sb.x, 0.0f);
                h[5] = fmaxf(qb.y + rb.y + fT * tb.y + fS * sb.y, 0.0f);
                h[6] = fmaxf(qb.z + rb.z + fT * tb.z + fS * sb.z, 0.0f);
                h[7] = fmaxf(qb.w + rb.w + fT * tb.w + fS * sb.w, 0.0f);
                bf16x8 H, L;
                #pragma unroll
                for (int u = 0; u < 8; ++u) {
                    const unsigned short hi = f2bf(h[u]);
                    H[u] = (short)hi;
                    L[u] = (short)f2bf(h[u] - bf2f(hi));
                }
                Bh[nt][kii] = H;
                Bl[nt][kii] = L;
            }
        }
        // MFMA over this ki-pair, all 4 m-tiles of our n-half
        #pragma unroll
        for (int kii = 0; kii < 2; ++kii) {
            const int ki = 2 * kp + kii;
            #pragma unroll
            for (int m = 0; m < 4; ++m) {
                const size_t off = (((size_t)ki * 8 + (4 * mh + m)) * 64 + l) * 8;
                const bf16x8 ah = *(const bf16x8*)(Wp + off);
                const bf16x8 al = *(const bf16x8*)(Wp + 16384 + off);
                __builtin_amdgcn_s_setprio(1);
                #pragma unroll
                for (int nt = 0; nt < 2; ++nt) {
                    acc[m][nt] = __builtin_amdgcn_mfma_f32_16x16x32_bf16(ah, Bh[nt][kii], acc[m][nt], 0, 0, 0);
                    acc[m][nt] = __builtin_amdgcn_mfma_f32_16x16x32_bf16(al, Bh[nt][kii], acc[m][nt], 0, 0, 0);
                    acc[m][nt] = __builtin_amdgcn_mfma_f32_16x16x32_bf16(ah, Bl[nt][kii], acc[m][nt], 0, 0, 0);
                }
                __builtin_amdgcn_s_setprio(0);
            }
        }
    }

    // ---- h2 = relu(acc) -> shared LDS [64e][128k] bf16 hi/lo (swizzled) ----
    #pragma unroll
    for (int m = 0; m < 4; ++m) {
        #pragma unroll
        for (int nt = 0; nt < 2; ++nt) {
            const int e = 32 * eh + 16 * nt + lr;
            const int nb = 2 * (64 * mh + 16 * m + 4 * lg);   // byte offset in row
            float v[4];
            v[0] = fmaxf(acc[m][nt][0], 0.0f);
            v[1] = fmaxf(acc[m][nt][1], 0.0f);
            v[2] = fmaxf(acc[m][nt][2], 0.0f);
            v[3] = fmaxf(acc[m][nt][3], 0.0f);
            bf16x4 H, L;
            #pragma unroll
            for (int u = 0; u < 4; ++u) {
                const unsigned short hi = f2bf(v[u]);
                H[u] = (short)hi;
                L[u] = (short)f2bf(v[u] - bf2f(hi));
            }
            const unsigned int ad = (unsigned int)e * 256 +
                (unsigned int)(nb ^ ((e & 7) << 4));
            *(bf16x4*)(hb8 + ad) = H;
            *(bf16x4*)(hb8 + 16384 + ad) = L;
        }
    }
    __syncthreads();   // barrier #1: h2 exchange across n-half waves

    // ---- layer 3: same edges, B from LDS (full k), acc re-init with b3 ----
    #pragma unroll
    for (int m = 0; m < 4; ++m) {
        const float4 bv = *(const float4*)&b3[64 * mh + 16 * m + 4 * lg];
        #pragma unroll
        for (int nt = 0; nt < 2; ++nt) {
            acc[m][nt][0] = bv.x; acc[m][nt][1] = bv.y;
            acc[m][nt][2] = bv.z; acc[m][nt][3] = bv.w;
        }
    }
    #pragma unroll
    for (int kp = 0; kp < 2; ++kp) {
        bf16x8 Bh[2][2], Bl[2][2];
        #pragma unroll
        for (int kii = 0; kii < 2; ++kii) {
            const int ki = 2 * kp + kii;
            #pragma unroll
            for (int nt = 0; nt < 2; ++nt) {
                const int e = 32 * eh + 16 * nt + lr;
                const unsigned int ad = (unsigned int)e * 256 +
                    (unsigned int)((64 * ki + 16 * lg) ^ ((e & 7) << 4));
                Bh[nt][kii] = *(const bf16x8*)(hb8 + ad);
                Bl[nt][kii] = *(const bf16x8*)(hb8 + 16384 + ad);
            }
        }
        #pragma unroll
        for (int kii = 0; kii < 2; ++kii) {
            const int ki = 2 * kp + kii;
            #pragma unroll
            for (int m = 0; m < 4; ++m) {
                const size_t off = (((size_t)ki * 8 + (4 * mh + m)) * 64 + l) * 8;
                const bf16x8 ah = *(const bf16x8*)(Wp + 32768 + off);
                const bf16x8 al = *(const bf16x8*)(Wp + 49152 + off);
                __builtin_amdgcn_s_setprio(1);
                #pragma unroll
                for (int nt = 0; nt < 2; ++nt) {
                    acc[m][nt] = __builtin_amdgcn_mfma_f32_16x16x32_bf16(ah, Bh[nt][kii], acc[m][nt], 0, 0, 0);
                    acc[m][nt] = __builtin_amdgcn_mfma_f32_16x16x32_bf16(al, Bh[nt][kii], acc[m][nt], 0, 0, 0);
                    acc[m][nt] = __builtin_amdgcn_mfma_f32_16x16x32_bf16(ah, Bl[nt][kii], acc[m][nt], 0, 0, 0);
                }
                __builtin_amdgcn_s_setprio(0);
            }
        }
    }

    // ---- LN partials: in-register + shfl over lg, cross-wave via 1KB LDS ----
    #pragma unroll
    for (int nt = 0; nt < 2; ++nt) {
        float s = 0.0f, s2 = 0.0f;
        #pragma unroll
        for (int m = 0; m < 4; ++m)
            #pragma unroll
            for (int r = 0; r < 4; ++r) {
                const float v = acc[m][nt][r];
                s += v;
                s2 = fmaf(v, v, s2);
            }
        s  += __shfl_xor(s, 16);  s  += __shfl_xor(s, 32);
        s2 += __shfl_xor(s2, 16); s2 += __shfl_xor(s2, 32);
        const int e = 32 * eh + 16 * nt + lr;
        if (lg == 0) {
            lnS[e * 2 + mh] = s;
            lnQ[e * 2 + mh] = s2;
        }
    }
    __syncthreads();   // barrier #2: LN cross-wave combine

    // ---- normalize in-register, mask, store fragments direct to global ----
    #pragma unroll
    for (int nt = 0; nt < 2; ++nt) {
        const int e = 32 * eh + 16 * nt + lr;
        const float st = lnS[e * 2 + 0] + lnS[e * 2 + 1];
        const float sq = lnQ[e * 2 + 0] + lnQ[e * 2 + 1];
        const float mu  = st * (1.0f / 128.0f);
        const float var = sq * (1.0f / 128.0f) - mu * mu;
        const float inv = rsqrtf(var + 1e-5f);
        const size_t erow = ((size_t)(b * NN + i)) * NN + (j0 + e);
        const float em = edge_mask[erow];
        float* op = out + erow * CP;
        #pragma unroll
        for (int m = 0; m < 4; ++m) {
            const int n0 = 64 * mh + 16 * m + 4 * lg;
            const float4 g4 = *(const float4*)&ln_g[n0];
            const float4 bb = *(const float4*)&ln_b[n0];
            float4 o;
            o.x = ((acc[m][nt][0] - mu) * inv * g4.x + bb.x) * em;
            o.y = ((acc[m][nt][1] - mu) * inv * g4.y + bb.y) * em;
            o.z = ((acc[m][nt][2] - mu) * inv * g4.z + bb.z) * em;
            o.w = ((acc[m][nt][3] - mu) * inv * g4.w + bb.w) * em;
            *(float4*)(op + n0) = o;
        }
    }
}

extern "C" void kernel_launch(void* const* d_in, const int* in_sizes, int n_in,
                              void* d_out, int out_size, void* d_ws, size_t ws_size,
                              hipStream_t stream) {
    const float* init_node = (const float*)d_in[0];
    const float* trans_t   = (const float*)d_in[1];
    const float* trans_sc  = (const float*)d_in[2];
    const float* edge_mask = (const float*)d_in[3];
    const float* diffuse   = (const float*)d_in[4];
    const float* Wsp       = (const float*)d_in[5];
    const float* bsp       = (const float*)d_in[6];
    const float* W1        = (const float*)d_in[7];
    const float* b1        = (const float*)d_in[8];
    const float* W2        = (const float*)d_in[9];
    const float* b2        = (const float*)d_in[10];
    const float* W3        = (const float*)d_in[11];
    const float* b3        = (const float*)d_in[12];
    const float* ln_g      = (const float*)d_in[13];
    const float* ln_b      = (const float*)d_in[14];
    float* out = (float*)d_out;
    float* qr  = (float*)d_ws;                                       // 1 MiB
    unsigned short* Wp = (unsigned short*)((char*)d_ws + (1 << 20)); // 128 KiB

    ef_prep_kernel<<<1024 + 64, 256, 0, stream>>>(
        init_node, diffuse, Wsp, bsp, W1, b1, W2, W3, qr, Wp);
    ef_edge_kernel<<<NB * NN * (NN / EPB), 256, 0, stream>>>(
        trans_t, trans_sc, edge_mask, W1, b2, b3, ln_g, ln_b, qr, Wp, out);
}

// Round 8
// 276.702 us; speedup vs baseline: 2.3255x; 1.0212x over previous
//
#include <hip/hip_runtime.h>
#include <hip/hip_bf16.h>
#include <math.h>

#define NB 2
#define NN 512
#define CS 256
#define CP 128
#define FD 64
#define NBINS 22
#define EPB 64

typedef __attribute__((ext_vector_type(8))) short bf16x8;
typedef __attribute__((ext_vector_type(4))) short bf16x4;
typedef __attribute__((ext_vector_type(4))) float f32x4;

__device__ __forceinline__ unsigned short f2bf_rne(float x) {
    unsigned int u = __float_as_uint(x);
    unsigned int r = (u + 0x7fffu + ((u >> 16) & 1u)) >> 16;
    return (unsigned short)r;
}
__device__ __forceinline__ float bf2f(unsigned short b) {
    return __uint_as_float(((unsigned int)b) << 16);
}
__device__ __forceinline__ unsigned short f2bf(float x) {
    __hip_bfloat16 h = __float2bfloat16(x);
    unsigned short u;
    __builtin_memcpy(&u, &h, 2);
    return u;
}

// Guarded-floor bin: exact fp32 boundary semantics of the reference scan.
__device__ __forceinline__ int bin_of(float d, float step) {
    const float fk = __fdiv_rn(__fsub_rn(d, 0.001f), step);
    int k0 = (int)fk;
    k0 = k0 < 1 ? 1 : (k0 > 20 ? 20 : k0);
    int row = -1;
    #pragma unroll
    for (int dk = -1; dk <= 1; ++dk) {
        const int k = k0 + dk;
        const float lo = __fadd_rn(0.001f, __fmul_rn((float)k, step));
        const float hi = (k == NBINS - 1)
                       ? 1e8f
                       : __fadd_rn(0.001f, __fmul_rn((float)(k + 1), step));
        row = (d > lo && d < hi) ? k : row;
    }
    return row;
}

// 512B-row LDS swizzle for the f32 h3 staging tile.
__device__ __forceinline__ unsigned int swz512(int e, int boff) {
    return (unsigned int)e * 512 +
           (unsigned int)(boff ^ ((e & 7) << 4) ^ (((boff >> 7) & 3) << 4));
}

// ---------------------------------------------------------------------------
// Prep kernel: blocks [0,1024) = per-node q/r precompute; [1024,1088) = W pack.
// ---------------------------------------------------------------------------
__global__ __launch_bounds__(256) void ef_prep_kernel(
    const float* __restrict__ x,
    const float* __restrict__ diffuse,
    const float* __restrict__ Wsp,
    const float* __restrict__ bsp,
    const float* __restrict__ W1,
    const float* __restrict__ b1,
    const float* __restrict__ W2,
    const float* __restrict__ W3,
    float* __restrict__ qr,
    unsigned short* __restrict__ Wp)
{
    __shared__ float xs[CS];
    __shared__ float ps[FD];
    const int t = threadIdx.x;
    if (blockIdx.x < 1024) {
        const int n = blockIdx.x;
        xs[t] = x[(size_t)n * CS + t];
        __syncthreads();
        if (t < FD) {
            float acc = bsp[t];
            #pragma unroll 8
            for (int k = 0; k < CS; ++k)
                acc = fmaf(xs[k], Wsp[k * FD + t], acc);
            ps[t] = acc;
        }
        __syncthreads();
        const float dm = diffuse[n];
        const int c = t & (CP - 1);
        if (t < CP) {
            float acc = b1[c] + dm * W1[172 * CP + c];
            #pragma unroll 8
            for (int k = 0; k < FD; ++k)
                acc = fmaf(ps[k], W1[k * CP + c], acc);
            qr[(size_t)n * CP + c] = acc;
        } else {
            float acc = dm * W1[173 * CP + c];
            #pragma unroll 8
            for (int k = 0; k < FD; ++k)
                acc = fmaf(ps[k], W1[(FD + k) * CP + c], acc);
            qr[(size_t)(1024 + n) * CP + c] = acc;
        }
    } else {
        const int s = (blockIdx.x - 1024) * 256 + t;   // 0..16383
        const int j    = s & 7;
        const int lane = (s >> 3) & 63;
        const int mt   = (s >> 9) & 7;
        const int ki   = s >> 12;
        const int k = 32 * ki + 8 * (lane >> 4) + j;
        const int n = 16 * mt + (lane & 15);
        const float w2 = W2[k * CP + n];
        const float w3 = W3[k * CP + n];
        const unsigned short h2 = f2bf_rne(w2);
        const unsigned short l2 = f2bf_rne(w2 - bf2f(h2));
        const unsigned short h3 = f2bf_rne(w3);
        const unsigned short l3 = f2bf_rne(w3 - bf2f(h3));
        Wp[s]         = h2;
        Wp[16384 + s] = l2;
        Wp[32768 + s] = h3;
        Wp[49152 + s] = l3;
    }
}

// ---------------------------------------------------------------------------
// Edge kernel: one 64-edge tile per block, 4 waves, shared accumulator,
// ki-rotated Wp prefetch, LDS-staged coalesced store.
// ---------------------------------------------------------------------------
__global__ __launch_bounds__(256, 4) void ef_edge_kernel(
    const float* __restrict__ trans_t,
    const float* __restrict__ trans_sc,
    const float* __restrict__ edge_mask,
    const float* __restrict__ W1,
    const float* __restrict__ b2,
    const float* __restrict__ b3,
    const float* __restrict__ ln_g,
    const float* __restrict__ ln_b,
    const float* __restrict__ qr,
    const unsigned short* __restrict__ Wp,
    float* __restrict__ out)
{
    __shared__ char hb8[32768];   // h1 hi/lo -> h2 hi/lo -> h3 f32

    const int t   = threadIdx.x;
    const int blk = blockIdx.x;
    const int jt  = blk & 7;
    const int i   = (blk >> 3) & (NN - 1);
    const int b   = blk >> 12;
    const int j0  = jt * EPB;
    const int nodeI  = b * NN + i;
    const int nodeJ0 = b * NN + j0;

    const int w  = t >> 6;
    const int l  = t & 63;
    const int lr = l & 15;
    const int lg = l >> 4;
    const int e1 = t >> 2;
    const int c0 = (t & 3) * 32;
    const int nj = nodeJ0 + e1;

    // ---- bins (per-thread, 4x redundant, no LDS, no barrier) ----
    const float step = __fdiv_rn(__fsub_rn(20.0f, 0.001f), 21.0f);
    float dx = __fsub_rn(trans_t[nodeI * 3 + 0], trans_t[nj * 3 + 0]);
    float dy = __fsub_rn(trans_t[nodeI * 3 + 1], trans_t[nj * 3 + 1]);
    float dz = __fsub_rn(trans_t[nodeI * 3 + 2], trans_t[nj * 3 + 2]);
    const float dT = sqrtf(__fadd_rn(__fadd_rn(__fmul_rn(dx, dx), __fmul_rn(dy, dy)), __fmul_rn(dz, dz)));
    dx = __fsub_rn(trans_sc[nodeI * 3 + 0], trans_sc[nj * 3 + 0]);
    dy = __fsub_rn(trans_sc[nodeI * 3 + 1], trans_sc[nj * 3 + 1]);
    dz = __fsub_rn(trans_sc[nodeI * 3 + 2], trans_sc[nj * 3 + 2]);
    const float dS = sqrtf(__fadd_rn(__fadd_rn(__fmul_rn(dx, dx), __fmul_rn(dy, dy)), __fmul_rn(dz, dz)));
    const int kT = bin_of(dT, step);
    const int kS = bin_of(dS, step);

    // ---- P1: h1 = relu(q_i + r_j + W1[binT] + W1[binS]) -> LDS hi/lo ----
    {
        const float fT = (kT < 0) ? 0.0f : 1.0f;
        const float fS = (kS < 0) ? 0.0f : 1.0f;
        const float* qrow = qr + (size_t)nodeI * CP + c0;
        const float* rrow = qr + (size_t)(1024 + nj) * CP + c0;
        const float* wTr  = W1 + (size_t)(kT < 0 ? 0 : 128 + kT) * CP + c0;
        const float* wSr  = W1 + (size_t)(kS < 0 ? 0 : 150 + kS) * CP + c0;
        #pragma unroll
        for (int ch = 0; ch < 4; ++ch) {
            const int cc = ch * 8;
            const float4 qa = *(const float4*)(qrow + cc);
            const float4 qb = *(const float4*)(qrow + cc + 4);
            const float4 ra = *(const float4*)(rrow + cc);
            const float4 rb = *(const float4*)(rrow + cc + 4);
            const float4 ta = *(const float4*)(wTr + cc);
            const float4 tb = *(const float4*)(wTr + cc + 4);
            const float4 sa = *(const float4*)(wSr + cc);
            const float4 sb = *(const float4*)(wSr + cc + 4);
            float h[8];
            h[0] = fmaxf(qa.x + ra.x + fT * ta.x + fS * sa.x, 0.0f);
            h[1] = fmaxf(qa.y + ra.y + fT * ta.y + fS * sa.y, 0.0f);
            h[2] = fmaxf(qa.z + ra.z + fT * ta.z + fS * sa.z, 0.0f);
            h[3] = fmaxf(qa.w + ra.w + fT * ta.w + fS * sa.w, 0.0f);
            h[4] = fmaxf(qb.x + rb.x + fT * tb.x + fS * sb.x, 0.0f);
            h[5] = fmaxf(qb.y + rb.y + fT * tb.y + fS * sb.y, 0.0f);
            h[6] = fmaxf(qb.z + rb.z + fT * tb.z + fS * sb.z, 0.0f);
            h[7] = fmaxf(qb.w + rb.w + fT * tb.w + fS * sb.w, 0.0f);
            bf16x8 H, L;
            #pragma unroll
            for (int u = 0; u < 8; ++u) {
                const unsigned short hi = f2bf(h[u]);
                H[u] = (short)hi;
                L[u] = (short)f2bf(h[u] - bf2f(hi));
            }
            const unsigned int ad = (unsigned int)e1 * 256 +
                (((unsigned int)(2 * (c0 + cc))) ^ (((unsigned int)e1 & 7) << 4));
            *(bf16x8*)(hb8 + ad) = H;
            *(bf16x8*)(hb8 + 16384 + ad) = L;
        }
    }
    __syncthreads();

    // ---- P2: layer-2 MFMA with ki-rotated Wp prefetch ----
    f32x4 acc[2][4];
    #pragma unroll
    for (int mt = 0; mt < 2; ++mt) {
        const float4 bv = *(const float4*)&b2[16 * (2 * w + mt) + 4 * lg];
        #pragma unroll
        for (int nt = 0; nt < 4; ++nt) {
            acc[mt][nt][0] = bv.x; acc[mt][nt][1] = bv.y;
            acc[mt][nt][2] = bv.z; acc[mt][nt][3] = bv.w;
        }
    }
    {
        bf16x8 ahc[2], alc[2];
        #pragma unroll
        for (int mt = 0; mt < 2; ++mt) {
            const size_t off = (((size_t)0 * 8 + (2 * w + mt)) * 64 + l) * 8;
            ahc[mt] = *(const bf16x8*)(Wp + off);
            alc[mt] = *(const bf16x8*)(Wp + 16384 + off);
        }
        #pragma unroll
        for (int ki = 0; ki < 4; ++ki) {
            bf16x8 ahn[2], aln[2];
            if (ki < 3) {
                #pragma unroll
                for (int mt = 0; mt < 2; ++mt) {
                    const size_t off = (((size_t)(ki + 1) * 8 + (2 * w + mt)) * 64 + l) * 8;
                    ahn[mt] = *(const bf16x8*)(Wp + off);
                    aln[mt] = *(const bf16x8*)(Wp + 16384 + off);
                }
            }
            bf16x8 bh[4], bl[4];
            #pragma unroll
            for (int nt = 0; nt < 4; ++nt) {
                const int e = 16 * nt + lr;
                const unsigned int ad = (unsigned int)e * 256 +
                    (((unsigned int)(64 * ki + 16 * lg)) ^ (((unsigned int)e & 7) << 4));
                bh[nt] = *(const bf16x8*)(hb8 + ad);
                bl[nt] = *(const bf16x8*)(hb8 + 16384 + ad);
            }
            __builtin_amdgcn_s_setprio(1);
            #pragma unroll
            for (int mt = 0; mt < 2; ++mt)
                #pragma unroll
                for (int nt = 0; nt < 4; ++nt) {
                    acc[mt][nt] = __builtin_amdgcn_mfma_f32_16x16x32_bf16(ahc[mt], bh[nt], acc[mt][nt], 0, 0, 0);
                    acc[mt][nt] = __builtin_amdgcn_mfma_f32_16x16x32_bf16(alc[mt], bh[nt], acc[mt][nt], 0, 0, 0);
                    acc[mt][nt] = __builtin_amdgcn_mfma_f32_16x16x32_bf16(ahc[mt], bl[nt], acc[mt][nt], 0, 0, 0);
                }
            __builtin_amdgcn_s_setprio(0);
            if (ki < 3) {
                #pragma unroll
                for (int mt = 0; mt < 2; ++mt) { ahc[mt] = ahn[mt]; alc[mt] = aln[mt]; }
            }
        }
    }
    __syncthreads();   // all waves done reading h1; hb reusable for h2

    // ---- P3: h2 = relu(acc), split, store transposed [e][n] hi/lo ----
    #pragma unroll
    for (int mt = 0; mt < 2; ++mt) {
        const int mtg = 2 * w + mt;
        #pragma unroll
        for (int nt = 0; nt < 4; ++nt) {
            const int e = 16 * nt + lr;
            float v[4];
            v[0] = fmaxf(acc[mt][nt][0], 0.0f);
            v[1] = fmaxf(acc[mt][nt][1], 0.0f);
            v[2] = fmaxf(acc[mt][nt][2], 0.0f);
            v[3] = fmaxf(acc[mt][nt][3], 0.0f);
            bf16x4 H, L;
            #pragma unroll
            for (int u = 0; u < 4; ++u) {
                const unsigned short hi = f2bf(v[u]);
                H[u] = (short)hi;
                L[u] = (short)f2bf(v[u] - bf2f(hi));
            }
            const unsigned int ad = (unsigned int)e * 256 +
                (((unsigned int)(32 * mtg + 8 * lg)) ^ (((unsigned int)e & 7) << 4));
            *(bf16x4*)(hb8 + ad) = H;
            *(bf16x4*)(hb8 + 16384 + ad) = L;
        }
    }
    __syncthreads();

    // ---- P4: layer-3 MFMA into the SAME acc (re-init with b3), prefetched ----
    #pragma unroll
    for (int mt = 0; mt < 2; ++mt) {
        const float4 bv = *(const float4*)&b3[16 * (2 * w + mt) + 4 * lg];
        #pragma unroll
        for (int nt = 0; nt < 4; ++nt) {
            acc[mt][nt][0] = bv.x; acc[mt][nt][1] = bv.y;
            acc[mt][nt][2] = bv.z; acc[mt][nt][3] = bv.w;
        }
    }
    {
        bf16x8 ahc[2], alc[2];
        #pragma unroll
        for (int mt = 0; mt < 2; ++mt) {
            const size_t off = (((size_t)0 * 8 + (2 * w + mt)) * 64 + l) * 8;
            ahc[mt] = *(const bf16x8*)(Wp + 32768 + off);
            alc[mt] = *(const bf16x8*)(Wp + 49152 + off);
        }
        #pragma unroll
        for (int ki = 0; ki < 4; ++ki) {
            bf16x8 ahn[2], aln[2];
            if (ki < 3) {
                #pragma unroll
                for (int mt = 0; mt < 2; ++mt) {
                    const size_t off = (((size_t)(ki + 1) * 8 + (2 * w + mt)) * 64 + l) * 8;
                    ahn[mt] = *(const bf16x8*)(Wp + 32768 + off);
                    aln[mt] = *(const bf16x8*)(Wp + 49152 + off);
                }
            }
            bf16x8 bh[4], bl[4];
            #pragma unroll
            for (int nt = 0; nt < 4; ++nt) {
                const int e = 16 * nt + lr;
                const unsigned int ad = (unsigned int)e * 256 +
                    (((unsigned int)(64 * ki + 16 * lg)) ^ (((unsigned int)e & 7) << 4));
                bh[nt] = *(const bf16x8*)(hb8 + ad);
                bl[nt] = *(const bf16x8*)(hb8 + 16384 + ad);
            }
            __builtin_amdgcn_s_setprio(1);
            #pragma unroll
            for (int mt = 0; mt < 2; ++mt)
                #pragma unroll
                for (int nt = 0; nt < 4; ++nt) {
                    acc[mt][nt] = __builtin_amdgcn_mfma_f32_16x16x32_bf16(ahc[mt], bh[nt], acc[mt][nt], 0, 0, 0);
                    acc[mt][nt] = __builtin_amdgcn_mfma_f32_16x16x32_bf16(alc[mt], bh[nt], acc[mt][nt], 0, 0, 0);
                    acc[mt][nt] = __builtin_amdgcn_mfma_f32_16x16x32_bf16(ahc[mt], bl[nt], acc[mt][nt], 0, 0, 0);
                }
            __builtin_amdgcn_s_setprio(0);
            if (ki < 3) {
                #pragma unroll
                for (int mt = 0; mt < 2; ++mt) { ahc[mt] = ahn[mt]; alc[mt] = aln[mt]; }
            }
        }
    }
    __syncthreads();   // all waves done reading h2; hb reusable for h3

    // ---- P5: h3 (biases already in acc) -> LDS f32 [64 e][128 n] ----
    #pragma unroll
    for (int mt = 0; mt < 2; ++mt) {
        const int mtg = 2 * w + mt;
        #pragma unroll
        for (int nt = 0; nt < 4; ++nt) {
            const int e = 16 * nt + lr;
            float4 vv;
            vv.x = acc[mt][nt][0]; vv.y = acc[mt][nt][1];
            vv.z = acc[mt][nt][2]; vv.w = acc[mt][nt][3];
            *(float4*)(hb8 + swz512(e, 64 * mtg + 16 * lg)) = vv;
        }
    }
    __syncthreads();

    // ---- P6: LayerNorm (exact two-pass fp32), mask, coalesced store ----
    {
        const int e = e1;
        float vals[32];
        float s = 0.0f;
        #pragma unroll
        for (int cc = 0; cc < 32; cc += 4) {
            const float4 v = *(const float4*)(hb8 + swz512(e, 4 * (c0 + cc)));
            vals[cc] = v.x; vals[cc + 1] = v.y; vals[cc + 2] = v.z; vals[cc + 3] = v.w;
            s += v.x + v.y + v.z + v.w;
        }
        s += __shfl_xor(s, 1);
        s += __shfl_xor(s, 2);
        const float mu = s * (1.0f / 128.0f);
        float s2 = 0.0f;
        #pragma unroll
        for (int cc = 0; cc < 32; ++cc) {
            const float d = vals[cc] - mu;
            s2 = fmaf(d, d, s2);
        }
        s2 += __shfl_xor(s2, 1);
        s2 += __shfl_xor(s2, 2);
        const float inv = rsqrtf(s2 * (1.0f / 128.0f) + 1e-5f);
        const size_t erow = ((size_t)(b * NN + i)) * NN + (j0 + e);
        const float em = edge_mask[erow];
        float* op = out + erow * CP + c0;
        #pragma unroll
        for (int cc = 0; cc < 32; cc += 4) {
            const float4 g  = *(const float4*)&ln_g[c0 + cc];
            const float4 be = *(const float4*)&ln_b[c0 + cc];
            float4 o4;
            o4.x = ((vals[cc + 0] - mu) * inv * g.x + be.x) * em;
            o4.y = ((vals[cc + 1] - mu) * inv * g.y + be.y) * em;
            o4.z = ((vals[cc + 2] - mu) * inv * g.z + be.z) * em;
            o4.w = ((vals[cc + 3] - mu) * inv * g.w + be.w) * em;
            *(float4*)&op[cc] = o4;
        }
    }
}

extern "C" void kernel_launch(void* const* d_in, const int* in_sizes, int n_in,
                              void* d_out, int out_size, void* d_ws, size_t ws_size,
                              hipStream_t stream) {
    const float* init_node = (const float*)d_in[0];
    const float* trans_t   = (const float*)d_in[1];
    const float* trans_sc  = (const float*)d_in[2];
    const float* edge_mask = (const float*)d_in[3];
    const float* diffuse   = (const float*)d_in[4];
    const float* Wsp       = (const float*)d_in[5];
    const float* bsp       = (const float*)d_in[6];
    const float* W1        = (const float*)d_in[7];
    const float* b1        = (const float*)d_in[8];
    const float* W2        = (const float*)d_in[9];
    const float* b2        = (const float*)d_in[10];
    const float* W3        = (const float*)d_in[11];
    const float* b3        = (const float*)d_in[12];
    const float* ln_g      = (const float*)d_in[13];
    const float* ln_b      = (const float*)d_in[14];
    float* out = (float*)d_out;
    float* qr  = (float*)d_ws;                                       // 1 MiB
    unsigned short* Wp = (unsigned short*)((char*)d_ws + (1 << 20)); // 128 KiB

    ef_prep_kernel<<<1024 + 64, 256, 0, stream>>>(
        init_node, diffuse, Wsp, bsp, W1, b1, W2, W3, qr, Wp);
    ef_edge_kernel<<<NB * NN * (NN / EPB), 256, 0, stream>>>(
        trans_t, trans_sc, edge_mask, W1, b2, b3, ln_g, ln_b, qr, Wp, out);
}

// Round 12
// 202.171 us; speedup vs baseline: 3.1829x; 1.3687x over previous
//
#include <hip/hip_runtime.h>
#include <hip/hip_bf16.h>
#include <math.h>

#define NB 2
#define NN 512
#define CS 256
#define CP 128
#define FD 64
#define NBINS 22
#define EPB 64

typedef __attribute__((ext_vector_type(8))) short bf16x8;
typedef __attribute__((ext_vector_type(4))) short bf16x4;
typedef __attribute__((ext_vector_type(4))) float f32x4;

__device__ __forceinline__ unsigned short f2bf_rne(float x) {
    unsigned int u = __float_as_uint(x);
    unsigned int r = (u + 0x7fffu + ((u >> 16) & 1u)) >> 16;
    return (unsigned short)r;
}
__device__ __forceinline__ float bf2f(unsigned short b) {
    return __uint_as_float(((unsigned int)b) << 16);
}
__device__ __forceinline__ unsigned short f2bf(float x) {
    __hip_bfloat16 h = __float2bfloat16(x);
    unsigned short u;
    __builtin_memcpy(&u, &h, 2);
    return u;
}

// Guarded-floor bin: exact fp32 boundary semantics of the reference scan.
__device__ __forceinline__ int bin_of(float d, float step) {
    const float fk = __fdiv_rn(__fsub_rn(d, 0.001f), step);
    int k0 = (int)fk;
    k0 = k0 < 1 ? 1 : (k0 > 20 ? 20 : k0);
    int row = -1;
    #pragma unroll
    for (int dk = -1; dk <= 1; ++dk) {
        const int k = k0 + dk;
        const float lo = __fadd_rn(0.001f, __fmul_rn((float)k, step));
        const float hi = (k == NBINS - 1)
                       ? 1e8f
                       : __fadd_rn(0.001f, __fmul_rn((float)(k + 1), step));
        row = (d > lo && d < hi) ? k : row;
    }
    return row;
}

// ---------------------------------------------------------------------------
// Prep kernel: blocks [0,1024) = per-node q/r precompute; [1024,1088) = W pack.
// Wp: [4][16384] ushort {W2h, W2l, W3h, W3l}, per-lane MFMA A-frag order.
// (W keeps BOTH hi and lo planes: the al·bh term is retained; only the
//  activation-lo plane is dropped.)
// ---------------------------------------------------------------------------
__global__ __launch_bounds__(256) void ef_prep_kernel(
    const float* __restrict__ x,
    const float* __restrict__ diffuse,
    const float* __restrict__ Wsp,
    const float* __restrict__ bsp,
    const float* __restrict__ W1,
    const float* __restrict__ b1,
    const float* __restrict__ W2,
    const float* __restrict__ W3,
    float* __restrict__ qr,
    unsigned short* __restrict__ Wp)
{
    __shared__ float xs[CS];
    __shared__ float ps[FD];
    const int t = threadIdx.x;
    if (blockIdx.x < 1024) {
        const int n = blockIdx.x;
        xs[t] = x[(size_t)n * CS + t];
        __syncthreads();
        if (t < FD) {
            float acc = bsp[t];
            #pragma unroll 8
            for (int k = 0; k < CS; ++k)
                acc = fmaf(xs[k], Wsp[k * FD + t], acc);
            ps[t] = acc;
        }
        __syncthreads();
        const float dm = diffuse[n];
        const int c = t & (CP - 1);
        if (t < CP) {
            float acc = b1[c] + dm * W1[172 * CP + c];
            #pragma unroll 8
            for (int k = 0; k < FD; ++k)
                acc = fmaf(ps[k], W1[k * CP + c], acc);
            qr[(size_t)n * CP + c] = acc;
        } else {
            float acc = dm * W1[173 * CP + c];
            #pragma unroll 8
            for (int k = 0; k < FD; ++k)
                acc = fmaf(ps[k], W1[(FD + k) * CP + c], acc);
            qr[(size_t)(1024 + n) * CP + c] = acc;
        }
    } else {
        const int s = (blockIdx.x - 1024) * 256 + t;   // 0..16383
        const int j    = s & 7;
        const int lane = (s >> 3) & 63;
        const int mt   = (s >> 9) & 7;
        const int ki   = s >> 12;
        const int k = 32 * ki + 8 * (lane >> 4) + j;
        const int n = 16 * mt + (lane & 15);
        const float w2 = W2[k * CP + n];
        const float w3 = W3[k * CP + n];
        const unsigned short h2 = f2bf_rne(w2);
        const unsigned short l2 = f2bf_rne(w2 - bf2f(h2));
        const unsigned short h3 = f2bf_rne(w3);
        const unsigned short l3 = f2bf_rne(w3 - bf2f(h3));
        Wp[s]         = h2;
        Wp[16384 + s] = l2;
        Wp[32768 + s] = h3;
        Wp[49152 + s] = l3;
    }
}

// ---------------------------------------------------------------------------
// Edge kernel (r3 champion structure, two deltas):
//   1. merged accumulator (one acc[2][4] reused for both GEMMs — r8-proven)
//   2. activation-lo plane dropped: C = (Wh+Wl)·h_bf16 (2 MFMAs per pair)
//      -> h LDS plane halves to 16 KB, P1/P3 lose all lo-split converts.
// Phases: bins | P1 h1->LDS | P2 MFMA | P3 h2->LDS | P4 MFMA | P5 LN partials
//         | P6 LN reduce | P7 normalize + mask + direct frag store. 6 barriers.
// ---------------------------------------------------------------------------
__global__ __launch_bounds__(256, 4) void ef_edge_kernel(
    const float* __restrict__ trans_t,
    const float* __restrict__ trans_sc,
    const float* __restrict__ edge_mask,
    const float* __restrict__ W1,
    const float* __restrict__ b2,
    const float* __restrict__ b3,
    const float* __restrict__ ln_g,
    const float* __restrict__ ln_b,
    const float* __restrict__ qr,
    const unsigned short* __restrict__ Wp,
    float* __restrict__ out)
{
    __shared__ unsigned short hb[8192];    // 16384 B: h1-plane, then h2-plane
    char* hb8 = (char*)hb;
    // LN scratch carved from hb after barrier 4 (h2 dead):
    float* psum_s  = (float*)hb8;            // [64][17]  (4352 B)
    float* pqsum_s = (float*)(hb8 + 4352);   // [64][17]  (4352 B)
    float* mus     = (float*)(hb8 + 8704);   // [64]
    float* invs    = (float*)(hb8 + 8960);   // [64]      (ends 9216 <= 16384)

    const int t   = threadIdx.x;
    const int blk = blockIdx.x;
    const int jt  = blk & 7;
    const int i   = (blk >> 3) & (NN - 1);
    const int b   = blk >> 12;
    const int j0  = jt * EPB;
    const int nodeI  = b * NN + i;
    const int nodeJ0 = b * NN + j0;

    const int w  = t >> 6;
    const int l  = t & 63;
    const int lr = l & 15;
    const int lg = l >> 4;
    const int e1 = t >> 2;
    const int c0 = (t & 3) * 32;
    const int nj = nodeJ0 + e1;

    // ---- bins (per-thread, 4x redundant, no LDS, no barrier) ----
    const float step = __fdiv_rn(__fsub_rn(20.0f, 0.001f), 21.0f);
    float dx = __fsub_rn(trans_t[nodeI * 3 + 0], trans_t[nj * 3 + 0]);
    float dy = __fsub_rn(trans_t[nodeI * 3 + 1], trans_t[nj * 3 + 1]);
    float dz = __fsub_rn(trans_t[nodeI * 3 + 2], trans_t[nj * 3 + 2]);
    const float dT = sqrtf(__fadd_rn(__fadd_rn(__fmul_rn(dx, dx), __fmul_rn(dy, dy)), __fmul_rn(dz, dz)));
    dx = __fsub_rn(trans_sc[nodeI * 3 + 0], trans_sc[nj * 3 + 0]);
    dy = __fsub_rn(trans_sc[nodeI * 3 + 1], trans_sc[nj * 3 + 1]);
    dz = __fsub_rn(trans_sc[nodeI * 3 + 2], trans_sc[nj * 3 + 2]);
    const float dS = sqrtf(__fadd_rn(__fadd_rn(__fmul_rn(dx, dx), __fmul_rn(dy, dy)), __fmul_rn(dz, dz)));
    const int kT = bin_of(dT, step);
    const int kS = bin_of(dS, step);

    // ---- P1: h1 = relu(q_i + r_j + W1[binT] + W1[binS]) -> LDS (H plane) ----
    {
        const float fT = (kT < 0) ? 0.0f : 1.0f;
        const float fS = (kS < 0) ? 0.0f : 1.0f;
        const float* qrow = qr + (size_t)nodeI * CP + c0;
        const float* rrow = qr + (size_t)(1024 + nj) * CP + c0;
        const float* wTr  = W1 + (size_t)(kT < 0 ? 0 : 128 + kT) * CP + c0;
        const float* wSr  = W1 + (size_t)(kS < 0 ? 0 : 150 + kS) * CP + c0;
        #pragma unroll
        for (int ch = 0; ch < 4; ++ch) {
            const int cc = ch * 8;
            const float4 qa = *(const float4*)(qrow + cc);
            const float4 qb = *(const float4*)(qrow + cc + 4);
            const float4 ra = *(const float4*)(rrow + cc);
            const float4 rb = *(const float4*)(rrow + cc + 4);
            const float4 ta = *(const float4*)(wTr + cc);
            const float4 tb = *(const float4*)(wTr + cc + 4);
            const float4 sa = *(const float4*)(wSr + cc);
            const float4 sb = *(const float4*)(wSr + cc + 4);
            float h[8];
            h[0] = fmaxf(qa.x + ra.x + fT * ta.x + fS * sa.x, 0.0f);
            h[1] = fmaxf(qa.y + ra.y + fT * ta.y + fS * sa.y, 0.0f);
            h[2] = fmaxf(qa.z + ra.z + fT * ta.z + fS * sa.z, 0.0f);
            h[3] = fmaxf(qa.w + ra.w + fT * ta.w + fS * sa.w, 0.0f);
            h[4] = fmaxf(qb.x + rb.x + fT * tb.x + fS * sb.x, 0.0f);
            h[5] = fmaxf(qb.y + rb.y + fT * tb.y + fS * sb.y, 0.0f);
            h[6] = fmaxf(qb.z + rb.z + fT * tb.z + fS * sb.z, 0.0f);
            h[7] = fmaxf(qb.w + rb.w + fT * tb.w + fS * sb.w, 0.0f);
            bf16x8 H;
            #pragma unroll
            for (int u = 0; u < 8; ++u)
                H[u] = (short)f2bf(h[u]);
            const unsigned int ad = (unsigned int)e1 * 256 +
                (((unsigned int)(2 * (c0 + cc))) ^ (((unsigned int)e1 & 7) << 4));
            *(bf16x8*)(hb8 + ad) = H;
        }
    }
    __syncthreads();   // barrier 1: h1 ready

    // ---- P2: layer-2 MFMA: C = (W2h + W2l) · h1_bf16 ----
    f32x4 acc[2][4];
    #pragma unroll
    for (int mt = 0; mt < 2; ++mt) {
        const float4 bv = *(const float4*)&b2[16 * (2 * w + mt) + 4 * lg];
        #pragma unroll
        for (int nt = 0; nt < 4; ++nt) {
            acc[mt][nt][0] = bv.x; acc[mt][nt][1] = bv.y;
            acc[mt][nt][2] = bv.z; acc[mt][nt][3] = bv.w;
        }
    }
    #pragma unroll
    for (int ki = 0; ki < 4; ++ki) {
        bf16x8 ah[2], al[2];
        #pragma unroll
        for (int mt = 0; mt < 2; ++mt) {
            const size_t off = (((size_t)ki * 8 + (2 * w + mt)) * 64 + l) * 8;
            ah[mt] = *(const bf16x8*)(Wp + off);
            al[mt] = *(const bf16x8*)(Wp + 16384 + off);
        }
        bf16x8 bh[4];
        #pragma unroll
        for (int nt = 0; nt < 4; ++nt) {
            const int e = 16 * nt + lr;
            const unsigned int ad = (unsigned int)e * 256 +
                (((unsigned int)(64 * ki + 16 * lg)) ^ (((unsigned int)e & 7) << 4));
            bh[nt] = *(const bf16x8*)(hb8 + ad);
        }
        __builtin_amdgcn_s_setprio(1);
        #pragma unroll
        for (int mt = 0; mt < 2; ++mt)
            #pragma unroll
            for (int nt = 0; nt < 4; ++nt) {
                acc[mt][nt] = __builtin_amdgcn_mfma_f32_16x16x32_bf16(ah[mt], bh[nt], acc[mt][nt], 0, 0, 0);
                acc[mt][nt] = __builtin_amdgcn_mfma_f32_16x16x32_bf16(al[mt], bh[nt], acc[mt][nt], 0, 0, 0);
            }
        __builtin_amdgcn_s_setprio(0);
    }
    __syncthreads();   // barrier 2: all h1 reads done; hb reusable for h2

    // ---- P3: h2 = relu(acc) -> LDS (H plane only), transposed [e][n] ----
    #pragma unroll
    for (int mt = 0; mt < 2; ++mt) {
        const int mtg = 2 * w + mt;
        #pragma unroll
        for (int nt = 0; nt < 4; ++nt) {
            const int e = 16 * nt + lr;
            bf16x4 H;
            H[0] = (short)f2bf(fmaxf(acc[mt][nt][0], 0.0f));
            H[1] = (short)f2bf(fmaxf(acc[mt][nt][1], 0.0f));
            H[2] = (short)f2bf(fmaxf(acc[mt][nt][2], 0.0f));
            H[3] = (short)f2bf(fmaxf(acc[mt][nt][3], 0.0f));
            const unsigned int ad = (unsigned int)e * 256 +
                (((unsigned int)(32 * mtg + 8 * lg)) ^ (((unsigned int)e & 7) << 4));
            *(bf16x4*)(hb8 + ad) = H;
        }
    }
    __syncthreads();   // barrier 3: h2 ready

    // ---- P4: layer-3 MFMA into the SAME acc (re-init with b3) ----
    #pragma unroll
    for (int mt = 0; mt < 2; ++mt) {
        const float4 bv = *(const float4*)&b3[16 * (2 * w + mt) + 4 * lg];
        #pragma unroll
        for (int nt = 0; nt < 4; ++nt) {
            acc[mt][nt][0] = bv.x; acc[mt][nt][1] = bv.y;
            acc[mt][nt][2] = bv.z; acc[mt][nt][3] = bv.w;
        }
    }
    #pragma unroll
    for (int ki = 0; ki < 4; ++ki) {
        bf16x8 ah[2], al[2];
        #pragma unroll
        for (int mt = 0; mt < 2; ++mt) {
            const size_t off = (((size_t)ki * 8 + (2 * w + mt)) * 64 + l) * 8;
            ah[mt] = *(const bf16x8*)(Wp + 32768 + off);
            al[mt] = *(const bf16x8*)(Wp + 49152 + off);
        }
        bf16x8 bh[4];
        #pragma unroll
        for (int nt = 0; nt < 4; ++nt) {
            const int e = 16 * nt + lr;
            const unsigned int ad = (unsigned int)e * 256 +
                (((unsigned int)(64 * ki + 16 * lg)) ^ (((unsigned int)e & 7) << 4));
            bh[nt] = *(const bf16x8*)(hb8 + ad);
        }
        __builtin_amdgcn_s_setprio(1);
        #pragma unroll
        for (int mt = 0; mt < 2; ++mt)
            #pragma unroll
            for (int nt = 0; nt < 4; ++nt) {
                acc[mt][nt] = __builtin_amdgcn_mfma_f32_16x16x32_bf16(ah[mt], bh[nt], acc[mt][nt], 0, 0, 0);
                acc[mt][nt] = __builtin_amdgcn_mfma_f32_16x16x32_bf16(al[mt], bh[nt], acc[mt][nt], 0, 0, 0);
            }
        __builtin_amdgcn_s_setprio(0);
    }
    __syncthreads();   // barrier 4: all h2 reads done; hb reusable for LN

    // ---- P5: LN partial sums -> [64][17] arrays (r3-proven) ----
    #pragma unroll
    for (int nt = 0; nt < 4; ++nt) {
        const int e = 16 * nt + lr;
        float s = 0.0f, s2 = 0.0f;
        #pragma unroll
        for (int mt = 0; mt < 2; ++mt)
            #pragma unroll
            for (int r = 0; r < 4; ++r) {
                const float v = acc[mt][nt][r];
                s += v;
                s2 = fmaf(v, v, s2);
            }
        psum_s[e * 17 + 4 * w + lg]  = s;
        pqsum_s[e * 17 + 4 * w + lg] = s2;
    }
    __syncthreads();   // barrier 5

    // ---- P6: LN reduce (redundant per thread, e = t & 63) ----
    {
        const int e = t & 63;
        float s = 0.0f, s2 = 0.0f;
        #pragma unroll
        for (int k = 0; k < 16; ++k) {
            s  += psum_s[e * 17 + k];
            s2 += pqsum_s[e * 17 + k];
        }
        const float mu  = s * (1.0f / 128.0f);
        const float var = s2 * (1.0f / 128.0f) - mu * mu;
        mus[e]  = mu;
        invs[e] = rsqrtf(var + 1e-5f);
    }
    __syncthreads();   // barrier 6

    // ---- P7: normalize fragments in-register, mask, direct frag store ----
    {
        float4 g4[2], bb4[2];
        #pragma unroll
        for (int mt = 0; mt < 2; ++mt) {
            const int n0 = 16 * (2 * w + mt) + 4 * lg;
            g4[mt]  = *(const float4*)&ln_g[n0];
            bb4[mt] = *(const float4*)&ln_b[n0];
        }
        #pragma unroll
        for (int nt = 0; nt < 4; ++nt) {
            const int e = 16 * nt + lr;
            const size_t erow = ((size_t)(b * NN + i)) * NN + (j0 + e);
            const float em  = edge_mask[erow];
            const float mu  = mus[e];
            const float inv = invs[e];
            float* op = out + erow * CP;
            #pragma unroll
            for (int mt = 0; mt < 2; ++mt) {
                const int n0 = 16 * (2 * w + mt) + 4 * lg;
                float4 o;
                o.x = ((acc[mt][nt][0] - mu) * inv * g4[mt].x + bb4[mt].x) * em;
                o.y = ((acc[mt][nt][1] - mu) * inv * g4[mt].y + bb4[mt].y) * em;
                o.z = ((acc[mt][nt][2] - mu) * inv * g4[mt].z + bb4[mt].z) * em;
                o.w = ((acc[mt][nt][3] - mu) * inv * g4[mt].w + bb4[mt].w) * em;
                *(float4*)(op + n0) = o;
            }
        }
    }
}

extern "C" void kernel_launch(void* const* d_in, const int* in_sizes, int n_in,
                              void* d_out, int out_size, void* d_ws, size_t ws_size,
                              hipStream_t stream) {
    const float* init_node = (const float*)d_in[0];
    const float* trans_t   = (const float*)d_in[1];
    const float* trans_sc  = (const float*)d_in[2];
    const float* edge_mask = (const float*)d_in[3];
    const float* diffuse   = (const float*)d_in[4];
    const float* Wsp       = (const float*)d_in[5];
    const float* bsp       = (const float*)d_in[6];
    const float* W1        = (const float*)d_in[7];
    const float* b1        = (const float*)d_in[8];
    const float* W2        = (const float*)d_in[9];
    const float* b2        = (const float*)d_in[10];
    const float* W3        = (const float*)d_in[11];
    const float* b3        = (const float*)d_in[12];
    const float* ln_g      = (const float*)d_in[13];
    const float* ln_b      = (const float*)d_in[14];
    float* out = (float*)d_out;
    float* qr  = (float*)d_ws;                                       // 1 MiB
    unsigned short* Wp = (unsigned short*)((char*)d_ws + (1 << 20)); // 128 KiB

    ef_prep_kernel<<<1024 + 64, 256, 0, stream>>>(
        init_node, diffuse, Wsp, bsp, W1, b1, W2, W3, qr, Wp);
    ef_edge_kernel<<<NB * NN * (NN / EPB), 256, 0, stream>>>(
        trans_t, trans_sc, edge_mask, W1, b2, b3, ln_g, ln_b, qr, Wp, out);
}